// Round 12
// baseline (317.116 us; speedup 1.0000x reference)
//
#include <hip/hip_runtime.h>
#include <math.h>

// ---------------- problem constants (match reference) ----------------
// N=50000, F_IN=128, HID=64, HEADS1=4 (C1=256), NUM_GRAPHS=64, slope=0.2

typedef unsigned short ushort_t;
typedef __bf16 bf16x8 __attribute__((ext_vector_type(8)));
typedef float  f32x4  __attribute__((ext_vector_type(4)));

__device__ inline float bf2f(ushort_t u) { return __uint_as_float((unsigned)u << 16); }
__device__ inline ushort_t f2bf(float x) {            // round-to-nearest-even
  unsigned b = __float_as_uint(x);
  return (ushort_t)((b + 0x7fff + ((b >> 16) & 1)) >> 16);
}
__device__ inline float leaky(float v) { return (v > 0.f) ? v : 0.2f * v; }

__device__ inline f32x4 mfma16(bf16x8 a, bf16x8 b, f32x4 c) {
  return __builtin_amdgcn_mfma_f32_16x16x32_bf16(a, b, c, 0, 0, 0);
}

// ---------------- B-operand pack helper ----------------
// frag layout: frag-lane fl = frag*64+lane; lane l holds j=0..7 with
// col=(l&15), k = kt*32 + (l>>4)*8 + j. A uses same k-slot convention.
__device__ inline void packB_one(const float* __restrict__ B, ushort_t* __restrict__ bh,
                                 ushort_t* __restrict__ bl, int K, int Nn, int t) {
  int KT = K >> 5;
  int l = t & 63, fb = t >> 6;
  int nt = fb / KT, kt = fb - nt * KT;
  int col = nt * 16 + (l & 15);
  int k0 = kt * 32 + (l >> 4) * 8;
  ushort_t h[8], lo[8];
  #pragma unroll
  for (int j = 0; j < 8; ++j) {
    float v = B[(size_t)(k0 + j) * Nn + col];
    h[j] = f2bf(v);
    lo[j] = f2bf(v - bf2f(h[j]));
  }
  size_t o = (size_t)t * 8;
  *(ushort4*)(bh + o)     = make_ushort4(h[0], h[1], h[2], h[3]);
  *(ushort4*)(bh + o + 4) = make_ushort4(h[4], h[5], h[6], h[7]);
  *(ushort4*)(bl + o)     = make_ushort4(lo[0], lo[1], lo[2], lo[3]);
  *(ushort4*)(bl + o + 4) = make_ushort4(lo[4], lo[5], lo[6], lo[7]);
}

// ---------------- fused setup: hist (real edges only) | gbounds | packB ----------------
// deg must be zeroed beforehand (hipMemsetAsync). Self-loops are NOT counted here;
// the scan adds +1 per node analytically.
__global__ void k_setup(const int* __restrict__ edst, int E, int* __restrict__ deg,
                        const int* __restrict__ batch, int N, int G,
                        int* __restrict__ gstart,
                        const float* __restrict__ W1, const float* __restrict__ W2,
                        ushort_t* __restrict__ B1h, ushort_t* __restrict__ B1l,
                        ushort_t* __restrict__ B2h, ushort_t* __restrict__ B2l,
                        int HB, int GBB) {
  int b = blockIdx.x, tid = threadIdx.x;
  if (b < HB) {
    int i = b * 256 + tid;
    if (i < E) atomicAdd(&deg[edst[i]], 1);
  } else if (b < HB + GBB) {
    int i = (b - HB) * 256 + tid;
    if (i < N) {
      int bb = batch[i];
      int bp = (i == 0) ? -1 : batch[i - 1];
      for (int g = bp + 1; g <= bb; ++g) gstart[g] = i;
      if (i == N - 1)
        for (int g = bb + 1; g <= G; ++g) gstart[g] = N;
    }
  } else {
    int t = (b - HB - GBB) * 256 + tid;
    if (t < 4096) packB_one(W1, B1h, B1l, 128, 256, t);            // 16 nf x 4 kt
    else if (t < 6144) packB_one(W2, B2h, B2l, 256, 64, t - 4096); // 4 nf x 8 kt
  }
}

// ---------------- 3-pass multi-block exclusive scan over (deg[i]+1) ----------------
__global__ void k_scan_bsum(const int* __restrict__ deg, int n, int* __restrict__ bsum) {
  __shared__ int ws[16];
  int tid = threadIdx.x, lane = tid & 63, wv = tid >> 6;
  int i = blockIdx.x * 1024 + tid;
  int v = (i < n) ? deg[i] + 1 : 0;
  #pragma unroll
  for (int off = 1; off < 64; off <<= 1) v += __shfl_xor(v, off);
  if (lane == 0) ws[wv] = v;
  __syncthreads();
  if (tid < 16) {
    int s = ws[tid];
    #pragma unroll
    for (int off = 1; off < 16; off <<= 1) s += __shfl_xor(s, off);
    if (tid == 0) bsum[blockIdx.x] = s;
  }
}

__global__ void k_scan_bbase(const int* __restrict__ bsum, int nb,
                             int* __restrict__ bbase, int* __restrict__ offsets, int n) {
  int lane = threadIdx.x & 63;
  int v = (lane < nb) ? bsum[lane] : 0;
  int x = v;
  #pragma unroll
  for (int off = 1; off < 64; off <<= 1) {
    int t = __shfl_up(x, off);
    if (lane >= off) x += t;
  }
  if (lane < nb) bbase[lane] = x - v;
  if (lane == nb - 1) offsets[n] = x;
}

__global__ void k_scan_final(const int* __restrict__ deg, int n,
                             const int* __restrict__ bbase,
                             int* __restrict__ offsets, int* __restrict__ cursor) {
  __shared__ int wsum[16];
  int tid = threadIdx.x, lane = tid & 63, wv = tid >> 6;
  int i = blockIdx.x * 1024 + tid;
  int v = (i < n) ? deg[i] + 1 : 0;
  int x = v;
  #pragma unroll
  for (int off = 1; off < 64; off <<= 1) {
    int t = __shfl_up(x, off);
    if (lane >= off) x += t;
  }
  if (lane == 63) wsum[wv] = x;
  __syncthreads();
  if (wv == 0 && lane < 16) {
    int s = wsum[lane];
    #pragma unroll
    for (int off = 1; off < 16; off <<= 1) {
      int t = __shfl_up(s, off);
      if (lane >= off) s += t;
    }
    wsum[lane] = s;
  }
  __syncthreads();
  int wbase = (wv == 0) ? 0 : wsum[wv - 1];
  int incl = bbase[blockIdx.x] + wbase + x;
  if (i < n) { int o = incl - v; offsets[i] = o; cursor[i] = o; }
}

// ---------------- MFMA GEMM + fused attention logits (device body) ----------------
// TERMS==3: A loaded DIRECTLY from f32 (in-register hi/lo split), 3-term product.
// TERMS==2: A from packed bf16 frags (Ah), 2-term product.
template<int KT, int TERMS, int WM>
__device__ void gemm_att_body(int bx, int by,
                              const float* __restrict__ Af32, const ushort_t* __restrict__ Ah,
                              const ushort_t* __restrict__ Bh, const ushort_t* __restrict__ Bl,
                              const float* __restrict__ a_srcW, const float* __restrict__ a_dstW,
                              ushort_t* __restrict__ hb, float* __restrict__ as_,
                              float* __restrict__ ad_, int M, int Nn, int H) {
  const int tid = threadIdx.x;
  const int w = tid >> 6, lane = tid & 63;
  const int wm = w & (WM - 1), wn = w / WM;
  const int m0w = bx * (WM * 32) + wm * 32;
  const int n0  = by * ((4 / WM) * 64) + wn * 64;
  const int head = n0 >> 6;
  const int mt0 = m0w >> 4, nt0 = n0 >> 4;

  const float* pX[2];
  int rowmi[2];
  const ushort_t* pAh[2];
  #pragma unroll
  for (int mi = 0; mi < 2; ++mi) {
    if constexpr (TERMS == 3) {
      rowmi[mi] = (mt0 + mi) * 16 + (lane & 15);
      pX[mi] = Af32 + (size_t)rowmi[mi] * (KT * 32) + ((lane >> 4) << 3);
    } else {
      size_t fa = (size_t)(mt0 + mi) * KT;
      pAh[mi] = Ah + fa * 512 + (size_t)lane * 8;
    }
  }
  const ushort_t* pBh[4];
  const ushort_t* pBl[4];
  #pragma unroll
  for (int ni = 0; ni < 4; ++ni) {
    size_t fb = (size_t)(nt0 + ni) * KT;
    pBh[ni] = Bh + fb * 512 + (size_t)lane * 8;
    pBl[ni] = Bl + fb * 512 + (size_t)lane * 8;
  }

  f32x4 acc[2][4];
  #pragma unroll
  for (int mi = 0; mi < 2; ++mi)
    #pragma unroll
    for (int ni = 0; ni < 4; ++ni)
      acc[mi][ni] = (f32x4){0.f, 0.f, 0.f, 0.f};

  for (int kt = 0; kt < KT; ++kt) {
    const size_t ko = (size_t)kt * 512;
    bf16x8 ahf[2], alf[2], bhf[4], blf[4];
    #pragma unroll
    for (int mi = 0; mi < 2; ++mi) {
      if constexpr (TERMS == 3) {
        float v[8] = {0.f, 0.f, 0.f, 0.f, 0.f, 0.f, 0.f, 0.f};
        if (rowmi[mi] < M) {
          float4 a = *(const float4*)(pX[mi] + kt * 32);
          float4 b = *(const float4*)(pX[mi] + kt * 32 + 4);
          v[0] = a.x; v[1] = a.y; v[2] = a.z; v[3] = a.w;
          v[4] = b.x; v[5] = b.y; v[6] = b.z; v[7] = b.w;
        }
        union { ushort_t u[8]; bf16x8 f; } uh, ul;
        #pragma unroll
        for (int j = 0; j < 8; ++j) {
          uh.u[j] = f2bf(v[j]);
          ul.u[j] = f2bf(v[j] - bf2f(uh.u[j]));
        }
        ahf[mi] = uh.f;
        alf[mi] = ul.f;
      } else {
        ahf[mi] = *(const bf16x8*)(pAh[mi] + ko);
      }
    }
    #pragma unroll
    for (int ni = 0; ni < 4; ++ni) {
      bhf[ni] = *(const bf16x8*)(pBh[ni] + ko);
      blf[ni] = *(const bf16x8*)(pBl[ni] + ko);
    }
    #pragma unroll
    for (int mi = 0; mi < 2; ++mi)
      #pragma unroll
      for (int ni = 0; ni < 4; ++ni) {
        if constexpr (TERMS == 3)
          acc[mi][ni] = mfma16(alf[mi], bhf[ni], acc[mi][ni]);
        acc[mi][ni] = mfma16(ahf[mi], blf[ni], acc[mi][ni]);
        acc[mi][ni] = mfma16(ahf[mi], bhf[ni], acc[mi][ni]);
      }
  }

  // epilogue: per-row head dots + bf16 store
  // D mapping: col = (lane&15) + ni*16, row = (lane>>4)*4 + reg + mi*16
  const int c16 = lane & 15, q = lane >> 4;
  float sv[4], dv[4];
  #pragma unroll
  for (int ni = 0; ni < 4; ++ni) {
    sv[ni] = a_srcW[head * 64 + ni * 16 + c16];
    dv[ni] = a_dstW[head * 64 + ni * 16 + c16];
  }
  #pragma unroll
  for (int mi = 0; mi < 2; ++mi) {
    #pragma unroll
    for (int r = 0; r < 4; ++r) {
      int gr = m0w + mi * 16 + q * 4 + r;
      float ps = acc[mi][0][r] * sv[0] + acc[mi][1][r] * sv[1] +
                 acc[mi][2][r] * sv[2] + acc[mi][3][r] * sv[3];
      float pd = acc[mi][0][r] * dv[0] + acc[mi][1][r] * dv[1] +
                 acc[mi][2][r] * dv[2] + acc[mi][3][r] * dv[3];
      #pragma unroll
      for (int off = 1; off < 16; off <<= 1) {
        ps += __shfl_xor(ps, off);
        pd += __shfl_xor(pd, off);
      }
      if (gr < M) {
        #pragma unroll
        for (int ni = 0; ni < 4; ++ni)
          hb[(size_t)gr * Nn + n0 + ni * 16 + c16] = f2bf(acc[mi][ni][r]);
        if (c16 == 0) { as_[gr * H + head] = ps; ad_[gr * H + head] = pd; }
      }
    }
  }
}

// ---------------- fused launch: scatter (first) | gemm1 ----------------
__global__ __launch_bounds__(256)
void k_scatter_gemm1(const int* __restrict__ esrc, const int* __restrict__ edst,
                     int E, int N, int* __restrict__ cursor, int2* __restrict__ sed,
                     int SCB,
                     const float* __restrict__ x,
                     const ushort_t* __restrict__ B1h, const ushort_t* __restrict__ B1l,
                     const float* __restrict__ as_w, const float* __restrict__ ad_w,
                     ushort_t* __restrict__ h1b, float* __restrict__ as1,
                     float* __restrict__ ad1, int GB1) {
  if (blockIdx.x < SCB) {
    int i = blockIdx.x * 256 + threadIdx.x;
    int EE = E + N;
    if (i < EE) {
      int d, s;
      if (i < E) { d = edst[i]; s = esrc[i]; }
      else       { d = i - E;   s = i - E;   }
      int pos = atomicAdd(&cursor[d], 1);
      sed[pos] = make_int2(s, d);
    }
  } else {
    int b = blockIdx.x - SCB;
    gemm_att_body<4, 3, 2>(b % GB1, b / GB1, x, nullptr, B1h, B1l,
                           as_w, ad_w, h1b, as1, ad1, N, 256, 4);
  }
}

// ---------------- standalone gemm2 ----------------
__global__ __launch_bounds__(256)
void k_gemm2(const ushort_t* __restrict__ A2h,
             const ushort_t* __restrict__ B2h, const ushort_t* __restrict__ B2l,
             const float* __restrict__ as_w, const float* __restrict__ ad_w,
             ushort_t* __restrict__ h2b, float* __restrict__ as2,
             float* __restrict__ ad2, int M) {
  gemm_att_body<8, 2, 4>(blockIdx.x, 0, nullptr, A2h, B2h, B2l,
                         as_w, ad_w, h2b, as2, ad2, M, 64, 1);
}

// ---------------- edge weight kernels (no-max softmax numerator) ----------------
__global__ void k_edgew1(const int2* __restrict__ sed, const float* __restrict__ as1,
                         const float* __restrict__ ad1, float* __restrict__ w1, int EE) {
  int t = blockIdx.x * blockDim.x + threadIdx.x;
  if (t >= EE * 4) return;
  int e = t >> 2, h = t & 3;
  int2 p = sed[e];
  w1[t] = __expf(leaky(as1[p.x * 4 + h] + ad1[p.y * 4 + h]));
}

__global__ void k_edgew2(const int2* __restrict__ sed, const float* __restrict__ as2,
                         const float* __restrict__ ad2, float* __restrict__ w2, int EE) {
  int e = blockIdx.x * blockDim.x + threadIdx.x;
  if (e >= EE) return;
  int2 p = sed[e];
  w2[e] = __expf(leaky(as2[p.x] + ad2[p.y]));
}

// ---------------- layer-1 aggregation (precomputed weights, unroll-8) ----------------
// Output written directly in gemm2's A-fragment layout.
__global__ void k_agg1(const ushort_t* __restrict__ h1b, const float* __restrict__ w1,
                       const int* __restrict__ offs, const int2* __restrict__ sed,
                       const float* __restrict__ b1, ushort_t* __restrict__ a2h, int N) {
  int gt = blockIdx.x * blockDim.x + threadIdx.x;
  int wid = gt >> 6, lane = gt & 63;
  if (wid >= N) return;
  int head = lane >> 4, sub = lane & 15, coff = sub << 2;
  int start = offs[wid], end = offs[wid + 1];

  float denom = 0.f;
  float4 acc = make_float4(0.f, 0.f, 0.f, 0.f);
  int e = start;
  for (; e + 8 <= end; e += 8) {
    int s0 = sed[e].x, s1 = sed[e + 1].x, s2 = sed[e + 2].x, s3 = sed[e + 3].x;
    int s4 = sed[e + 4].x, s5 = sed[e + 5].x, s6 = sed[e + 6].x, s7 = sed[e + 7].x;
    float wa = w1[(e + 0) * 4 + head], wb = w1[(e + 1) * 4 + head];
    float wc = w1[(e + 2) * 4 + head], wd = w1[(e + 3) * 4 + head];
    float we = w1[(e + 4) * 4 + head], wf = w1[(e + 5) * 4 + head];
    float wg = w1[(e + 6) * 4 + head], wh = w1[(e + 7) * 4 + head];
    ushort4 g0 = *(const ushort4*)(h1b + (size_t)s0 * 256 + head * 64 + coff);
    ushort4 g1 = *(const ushort4*)(h1b + (size_t)s1 * 256 + head * 64 + coff);
    ushort4 g2 = *(const ushort4*)(h1b + (size_t)s2 * 256 + head * 64 + coff);
    ushort4 g3 = *(const ushort4*)(h1b + (size_t)s3 * 256 + head * 64 + coff);
    ushort4 g4 = *(const ushort4*)(h1b + (size_t)s4 * 256 + head * 64 + coff);
    ushort4 g5 = *(const ushort4*)(h1b + (size_t)s5 * 256 + head * 64 + coff);
    ushort4 g6 = *(const ushort4*)(h1b + (size_t)s6 * 256 + head * 64 + coff);
    ushort4 g7 = *(const ushort4*)(h1b + (size_t)s7 * 256 + head * 64 + coff);
    denom += ((wa + wb) + (wc + wd)) + ((we + wf) + (wg + wh));
    acc.x += wa * bf2f(g0.x) + wb * bf2f(g1.x) + wc * bf2f(g2.x) + wd * bf2f(g3.x)
           + we * bf2f(g4.x) + wf * bf2f(g5.x) + wg * bf2f(g6.x) + wh * bf2f(g7.x);
    acc.y += wa * bf2f(g0.y) + wb * bf2f(g1.y) + wc * bf2f(g2.y) + wd * bf2f(g3.y)
           + we * bf2f(g4.y) + wf * bf2f(g5.y) + wg * bf2f(g6.y) + wh * bf2f(g7.y);
    acc.z += wa * bf2f(g0.z) + wb * bf2f(g1.z) + wc * bf2f(g2.z) + wd * bf2f(g3.z)
           + we * bf2f(g4.z) + wf * bf2f(g5.z) + wg * bf2f(g6.z) + wh * bf2f(g7.z);
    acc.w += wa * bf2f(g0.w) + wb * bf2f(g1.w) + wc * bf2f(g2.w) + wd * bf2f(g3.w)
           + we * bf2f(g4.w) + wf * bf2f(g5.w) + wg * bf2f(g6.w) + wh * bf2f(g7.w);
  }
  for (; e + 4 <= end; e += 4) {
    int s0 = sed[e].x, s1 = sed[e + 1].x, s2 = sed[e + 2].x, s3 = sed[e + 3].x;
    float wa = w1[(e + 0) * 4 + head], wb = w1[(e + 1) * 4 + head];
    float wc = w1[(e + 2) * 4 + head], wd = w1[(e + 3) * 4 + head];
    ushort4 g0 = *(const ushort4*)(h1b + (size_t)s0 * 256 + head * 64 + coff);
    ushort4 g1 = *(const ushort4*)(h1b + (size_t)s1 * 256 + head * 64 + coff);
    ushort4 g2 = *(const ushort4*)(h1b + (size_t)s2 * 256 + head * 64 + coff);
    ushort4 g3 = *(const ushort4*)(h1b + (size_t)s3 * 256 + head * 64 + coff);
    denom += (wa + wb) + (wc + wd);
    acc.x += wa * bf2f(g0.x) + wb * bf2f(g1.x) + wc * bf2f(g2.x) + wd * bf2f(g3.x);
    acc.y += wa * bf2f(g0.y) + wb * bf2f(g1.y) + wc * bf2f(g2.y) + wd * bf2f(g3.y);
    acc.z += wa * bf2f(g0.z) + wb * bf2f(g1.z) + wc * bf2f(g2.z) + wd * bf2f(g3.z);
    acc.w += wa * bf2f(g0.w) + wb * bf2f(g1.w) + wc * bf2f(g2.w) + wd * bf2f(g3.w);
  }
  for (; e < end; ++e) {
    int s = sed[e].x;
    float w = w1[e * 4 + head];
    ushort4 g = *(const ushort4*)(h1b + (size_t)s * 256 + head * 64 + coff);
    denom += w;
    acc.x += w * bf2f(g.x); acc.y += w * bf2f(g.y);
    acc.z += w * bf2f(g.z); acc.w += w * bf2f(g.w);
  }
  float inv = 1.f / denom;
  float4 bv = *(const float4*)(b1 + head * 64 + coff);
  // packed write into gemm2 A-fragment layout
  int c0 = head * 64 + coff;
  int fa = (wid >> 4) * 8 + (c0 >> 5);
  int fl = (wid & 15) | (((c0 >> 3) & 3) << 4);
  size_t addr = ((size_t)fa * 64 + fl) * 8 + (c0 & 7);
  ushort4 o;
  o.x = f2bf(fmaxf(acc.x * inv + bv.x, 0.f));
  o.y = f2bf(fmaxf(acc.y * inv + bv.y, 0.f));
  o.z = f2bf(fmaxf(acc.z * inv + bv.z, 0.f));
  o.w = f2bf(fmaxf(acc.w * inv + bv.w, 0.f));
  *(ushort4*)(a2h + addr) = o;
}

// ---------------- layer-2 aggregation: half-wave edge pairing ----------------
__global__ void k_agg2(const ushort_t* __restrict__ h2b, const float* __restrict__ w2,
                       const int* __restrict__ offs, const int2* __restrict__ sed,
                       const float* __restrict__ b2, float* __restrict__ hfin, int N) {
  int gt = blockIdx.x * blockDim.x + threadIdx.x;
  int wid = gt >> 6, lane = gt & 63;
  if (wid >= N) return;
  int half = lane >> 5, li = lane & 31;
  int start = offs[wid], end = offs[wid + 1];

  float dn = 0.f, acc0 = 0.f, acc1 = 0.f;
  int e = start;
  for (; e + 8 <= end; e += 8) {
    int e0 = e + half, e1 = e + 2 + half, e2 = e + 4 + half, e3 = e + 6 + half;
    int s0 = sed[e0].x, s1 = sed[e1].x, s2 = sed[e2].x, s3 = sed[e3].x;
    float wa = w2[e0], wb = w2[e1], wc = w2[e2], wd = w2[e3];
    unsigned g0 = *(const unsigned*)(h2b + (size_t)s0 * 64 + li * 2);
    unsigned g1 = *(const unsigned*)(h2b + (size_t)s1 * 64 + li * 2);
    unsigned g2 = *(const unsigned*)(h2b + (size_t)s2 * 64 + li * 2);
    unsigned g3 = *(const unsigned*)(h2b + (size_t)s3 * 64 + li * 2);
    dn += (wa + wb) + (wc + wd);
    acc0 += wa * __uint_as_float(g0 << 16) + wb * __uint_as_float(g1 << 16)
          + wc * __uint_as_float(g2 << 16) + wd * __uint_as_float(g3 << 16);
    acc1 += wa * __uint_as_float(g0 & 0xffff0000u) + wb * __uint_as_float(g1 & 0xffff0000u)
          + wc * __uint_as_float(g2 & 0xffff0000u) + wd * __uint_as_float(g3 & 0xffff0000u);
  }
  for (; e + 2 <= end; e += 2) {
    int e0 = e + half;
    int s0 = sed[e0].x;
    float wa = w2[e0];
    unsigned g0 = *(const unsigned*)(h2b + (size_t)s0 * 64 + li * 2);
    dn += wa;
    acc0 += wa * __uint_as_float(g0 << 16);
    acc1 += wa * __uint_as_float(g0 & 0xffff0000u);
  }
  if (e < end && half == 0) {   // odd leftover edge
    int s0 = sed[e].x;
    float wa = w2[e];
    unsigned g0 = *(const unsigned*)(h2b + (size_t)s0 * 64 + li * 2);
    dn += wa;
    acc0 += wa * __uint_as_float(g0 << 16);
    acc1 += wa * __uint_as_float(g0 & 0xffff0000u);
  }
  acc0 += __shfl_xor(acc0, 32);
  acc1 += __shfl_xor(acc1, 32);
  dn   += __shfl_xor(dn, 32);
  if (half == 0) {
    float inv = 1.f / dn;
    float2 bv = *(const float2*)(b2 + li * 2);
    float2 o;
    o.x = acc0 * inv + bv.x;
    o.y = acc1 * inv + bv.y;
    *(float2*)(hfin + (size_t)wid * 64 + li * 2) = o;
  }
}

// ---------------- global mean pool (batch is sorted) ----------------
__global__ void k_pool(const float* __restrict__ hfin, const int* __restrict__ gstart,
                       float* __restrict__ out) {
  int g = blockIdx.x;
  int c = threadIdx.x & 63, r = threadIdx.x >> 6;
  int start = gstart[g], cnt = gstart[g + 1] - start;
  float acc = 0.f;
  for (int i = r; i < cnt; i += 4)
    acc += hfin[(size_t)(start + i) * 64 + c];
  __shared__ float red[256];
  red[threadIdx.x] = acc;
  __syncthreads();
  if (r == 0)
    out[g * 64 + c] = (red[c] + red[64 + c] + red[128 + c] + red[192 + c]) /
                      fmaxf((float)cnt, 1.f);
}

// ---------------- launcher ----------------
extern "C" void kernel_launch(void* const* d_in, const int* in_sizes, int n_in,
                              void* d_out, int out_size, void* d_ws, size_t ws_size,
                              hipStream_t stream) {
  const float* x        = (const float*)d_in[0];
  const int*   ei       = (const int*)d_in[1];
  const int*   batch    = (const int*)d_in[2];
  const float* W1       = (const float*)d_in[3];
  const float* att_src1 = (const float*)d_in[4];
  const float* att_dst1 = (const float*)d_in[5];
  const float* b1       = (const float*)d_in[6];
  const float* W2       = (const float*)d_in[7];
  const float* att_src2 = (const float*)d_in[8];
  const float* att_dst2 = (const float*)d_in[9];
  const float* b2       = (const float*)d_in[10];
  float* out = (float*)d_out;

  const int N = in_sizes[0] / 128;   // 50000
  const int E = in_sizes[1] / 2;     // 800000
  const int EE = E + N;
  const int* esrc = ei;
  const int* edst = ei + E;

  const int GB2 = (N + 127) / 128;       // gemm2 blocks (128 rows)
  const int GB1 = GB2 * 2;               // gemm1 x-blocks (64 rows)
  const int MF  = GB2 * 8;               // padded m-frags (rows/16)
  const int NB  = (N + 1023) / 1024;     // scan blocks (<= 64)
  const int HB  = (E + 255) / 256;       // hist blocks
  const int GBB = (N + 255) / 256;       // gbounds blocks
  const int SCB = (EE + 255) / 256;      // scatter blocks

  // workspace carve (256B aligned)
  char* p = (char*)d_ws;
  auto alloc = [&](size_t bytes) -> void* {
    void* r = (void*)p;
    p += (bytes + 255) & ~(size_t)255;
    return r;
  };
  ushort_t* A2h  = (ushort_t*)alloc((size_t)MF * 8 * 64 * 16);  // written by k_agg1
  ushort_t* B1h  = (ushort_t*)alloc((size_t)16 * 4 * 64 * 16);
  ushort_t* B1l  = (ushort_t*)alloc((size_t)16 * 4 * 64 * 16);
  ushort_t* B2h  = (ushort_t*)alloc((size_t)4 * 8 * 64 * 16);
  ushort_t* B2l  = (ushort_t*)alloc((size_t)4 * 8 * 64 * 16);
  ushort_t* h1b  = (ushort_t*)alloc((size_t)N * 256 * 2);
  ushort_t* h2b  = (ushort_t*)alloc((size_t)N * 64 * 2);
  float*    hfin = (float*)alloc((size_t)N * 64 * 4);
  float*    as1  = (float*)alloc((size_t)N * 4 * 4);
  float*    ad1  = (float*)alloc((size_t)N * 4 * 4);
  float*    as2  = (float*)alloc((size_t)N * 4);
  float*    ad2  = (float*)alloc((size_t)N * 4);
  float*    w1   = (float*)alloc((size_t)EE * 4 * 4);
  float*    w2   = (float*)alloc((size_t)EE * 4);
  int*  deg     = (int*)alloc((size_t)N * 4);
  int*  offsets = (int*)alloc((size_t)(N + 1) * 4);
  int*  cursor  = (int*)alloc((size_t)N * 4);
  int2* sed     = (int2*)alloc((size_t)EE * 8);
  int*  bsum    = (int*)alloc(64 * 4);
  int*  bbase   = (int*)alloc(64 * 4);
  int*  gstart  = (int*)alloc(65 * 4);

  // --- zero degree array (async, capture-safe) ---
  hipMemsetAsync(deg, 0, (size_t)N * 4, stream);

  // --- fused setup: hist | gbounds | packB ---
  k_setup<<<HB + GBB + 24, 256, 0, stream>>>(edst, E, deg, batch, N, 64, gstart,
                                             W1, W2, B1h, B1l, B2h, B2l, HB, GBB);

  // --- scan over deg+1 ---
  k_scan_bsum<<<NB, 1024, 0, stream>>>(deg, N, bsum);
  k_scan_bbase<<<1, 64, 0, stream>>>(bsum, NB, bbase, offsets, N);
  k_scan_final<<<NB, 1024, 0, stream>>>(deg, N, bbase, offsets, cursor);

  // --- fused: scatter | gemm1 (independent; co-resident) ---
  k_scatter_gemm1<<<SCB + GB1 * 2, 256, 0, stream>>>(
      esrc, edst, E, N, cursor, sed, SCB,
      x, B1h, B1l, att_src1, att_dst1, h1b, as1, ad1, GB1);

  // --- layer-1 edge weights + aggregation ---
  k_edgew1<<<(EE * 4 + 255) / 256, 256, 0, stream>>>(sed, as1, ad1, w1, EE);
  int wave_blocks = (N * 64 + 255) / 256;
  k_agg1<<<wave_blocks, 256, 0, stream>>>(h1b, w1, offsets, sed, b1, A2h, N);

  // --- layer 2 ---
  k_gemm2<<<GB2, 256, 0, stream>>>(A2h, B2h, B2l, att_src2, att_dst2,
                                   h2b, as2, ad2, N);
  k_edgew2<<<(EE + 255) / 256, 256, 0, stream>>>(sed, as2, ad2, w2, EE);
  k_agg2<<<wave_blocks, 256, 0, stream>>>(h2b, w2, offsets, sed, b2, hfin, N);

  // --- global mean pool ---
  k_pool<<<64, 256, 0, stream>>>(hfin, gstart, out);
}

// Round 13
// 302.608 us; speedup vs baseline: 1.0479x; 1.0479x over previous
//
#include <hip/hip_runtime.h>
#include <math.h>

// ---------------- problem constants (match reference) ----------------
// N=50000, F_IN=128, HID=64, HEADS1=4 (C1=256), NUM_GRAPHS=64, slope=0.2

typedef unsigned short ushort_t;
typedef __bf16 bf16x8 __attribute__((ext_vector_type(8)));
typedef float  f32x4  __attribute__((ext_vector_type(4)));

__device__ inline float bf2f(ushort_t u) { return __uint_as_float((unsigned)u << 16); }
__device__ inline ushort_t f2bf(float x) {            // round-to-nearest-even
  unsigned b = __float_as_uint(x);
  return (ushort_t)((b + 0x7fff + ((b >> 16) & 1)) >> 16);
}
__device__ inline float leaky(float v) { return (v > 0.f) ? v : 0.2f * v; }

__device__ inline f32x4 mfma16(bf16x8 a, bf16x8 b, f32x4 c) {
  return __builtin_amdgcn_mfma_f32_16x16x32_bf16(a, b, c, 0, 0, 0);
}

// ---------------- B-operand pack helper ----------------
// frag layout: frag-lane fl = frag*64+lane; lane l holds j=0..7 with
// col=(l&15), k = kt*32 + (l>>4)*8 + j. A uses same k-slot convention.
__device__ inline void packB_one(const float* __restrict__ B, ushort_t* __restrict__ bh,
                                 ushort_t* __restrict__ bl, int K, int Nn, int t) {
  int KT = K >> 5;
  int l = t & 63, fb = t >> 6;
  int nt = fb / KT, kt = fb - nt * KT;
  int col = nt * 16 + (l & 15);
  int k0 = kt * 32 + (l >> 4) * 8;
  ushort_t h[8], lo[8];
  #pragma unroll
  for (int j = 0; j < 8; ++j) {
    float v = B[(size_t)(k0 + j) * Nn + col];
    h[j] = f2bf(v);
    lo[j] = f2bf(v - bf2f(h[j]));
  }
  size_t o = (size_t)t * 8;
  *(ushort4*)(bh + o)     = make_ushort4(h[0], h[1], h[2], h[3]);
  *(ushort4*)(bh + o + 4) = make_ushort4(h[4], h[5], h[6], h[7]);
  *(ushort4*)(bl + o)     = make_ushort4(lo[0], lo[1], lo[2], lo[3]);
  *(ushort4*)(bl + o + 4) = make_ushort4(lo[4], lo[5], lo[6], lo[7]);
}

// ---------------- fused setup: hist (real edges only) | gbounds | packB ----------------
// deg zeroed beforehand (hipMemsetAsync). Self-loops NOT counted; scan adds +1/node.
__global__ void k_setup(const int* __restrict__ edst, int E, int* __restrict__ deg,
                        const int* __restrict__ batch, int N, int G,
                        int* __restrict__ gstart,
                        const float* __restrict__ W1, const float* __restrict__ W2,
                        ushort_t* __restrict__ B1h, ushort_t* __restrict__ B1l,
                        ushort_t* __restrict__ B2h, ushort_t* __restrict__ B2l,
                        int HB, int GBB) {
  int b = blockIdx.x, tid = threadIdx.x;
  if (b < HB) {
    int i = b * 256 + tid;
    if (i < E) atomicAdd(&deg[edst[i]], 1);
  } else if (b < HB + GBB) {
    int i = (b - HB) * 256 + tid;
    if (i < N) {
      int bb = batch[i];
      int bp = (i == 0) ? -1 : batch[i - 1];
      for (int g = bp + 1; g <= bb; ++g) gstart[g] = i;
      if (i == N - 1)
        for (int g = bb + 1; g <= G; ++g) gstart[g] = N;
    }
  } else {
    int t = (b - HB - GBB) * 256 + tid;
    if (t < 4096) packB_one(W1, B1h, B1l, 128, 256, t);            // 16 nf x 4 kt
    else if (t < 6144) packB_one(W2, B2h, B2l, 256, 64, t - 4096); // 4 nf x 8 kt
  }
}

// ---------------- 3-pass multi-block exclusive scan over (deg[i]+1) ----------------
__global__ void k_scan_bsum(const int* __restrict__ deg, int n, int* __restrict__ bsum) {
  __shared__ int ws[16];
  int tid = threadIdx.x, lane = tid & 63, wv = tid >> 6;
  int i = blockIdx.x * 1024 + tid;
  int v = (i < n) ? deg[i] + 1 : 0;
  #pragma unroll
  for (int off = 1; off < 64; off <<= 1) v += __shfl_xor(v, off);
  if (lane == 0) ws[wv] = v;
  __syncthreads();
  if (tid < 16) {
    int s = ws[tid];
    #pragma unroll
    for (int off = 1; off < 16; off <<= 1) s += __shfl_xor(s, off);
    if (tid == 0) bsum[blockIdx.x] = s;
  }
}

__global__ void k_scan_bbase(const int* __restrict__ bsum, int nb,
                             int* __restrict__ bbase, int* __restrict__ offsets, int n) {
  int lane = threadIdx.x & 63;
  int v = (lane < nb) ? bsum[lane] : 0;
  int x = v;
  #pragma unroll
  for (int off = 1; off < 64; off <<= 1) {
    int t = __shfl_up(x, off);
    if (lane >= off) x += t;
  }
  if (lane < nb) bbase[lane] = x - v;
  if (lane == nb - 1) offsets[n] = x;
}

__global__ void k_scan_final(const int* __restrict__ deg, int n,
                             const int* __restrict__ bbase,
                             int* __restrict__ offsets, int* __restrict__ cursor) {
  __shared__ int wsum[16];
  int tid = threadIdx.x, lane = tid & 63, wv = tid >> 6;
  int i = blockIdx.x * 1024 + tid;
  int v = (i < n) ? deg[i] + 1 : 0;
  int x = v;
  #pragma unroll
  for (int off = 1; off < 64; off <<= 1) {
    int t = __shfl_up(x, off);
    if (lane >= off) x += t;
  }
  if (lane == 63) wsum[wv] = x;
  __syncthreads();
  if (wv == 0 && lane < 16) {
    int s = wsum[lane];
    #pragma unroll
    for (int off = 1; off < 16; off <<= 1) {
      int t = __shfl_up(s, off);
      if (lane >= off) s += t;
    }
    wsum[lane] = s;
  }
  __syncthreads();
  int wbase = (wv == 0) ? 0 : wsum[wv - 1];
  int incl = bbase[blockIdx.x] + wbase + x;
  if (i < n) { int o = incl - v; offsets[i] = o; cursor[i] = o; }
}

// ---------------- scatter: dst-sorted (src,dst) pairs, grid-stride ----------------
__global__ void k_scatter(const int* __restrict__ esrc, const int* __restrict__ edst,
                          int E, int N, int* __restrict__ cursor,
                          int2* __restrict__ sed) {
  int stride = gridDim.x * blockDim.x;
  int EE = E + N;
  for (int i = blockIdx.x * blockDim.x + threadIdx.x; i < EE; i += stride) {
    int d, s;
    if (i < E) { d = edst[i]; s = esrc[i]; }
    else       { d = i - E;   s = i - E;   }
    int pos = atomicAdd(&cursor[d], 1);
    sed[pos] = make_int2(s, d);
  }
}

// ---------------- MFMA GEMM + fused attention logits (device body) ----------------
// TERMS==3: A loaded DIRECTLY from f32 (in-register hi/lo split), 3-term product.
// TERMS==2: A from packed bf16 frags (Ah), 2-term product.
template<int KT, int TERMS, int WM>
__device__ void gemm_att_body(int bx, int by,
                              const float* __restrict__ Af32, const ushort_t* __restrict__ Ah,
                              const ushort_t* __restrict__ Bh, const ushort_t* __restrict__ Bl,
                              const float* __restrict__ a_srcW, const float* __restrict__ a_dstW,
                              ushort_t* __restrict__ hb, float* __restrict__ as_,
                              float* __restrict__ ad_, int M, int Nn, int H) {
  const int tid = threadIdx.x;
  const int w = tid >> 6, lane = tid & 63;
  const int wm = w & (WM - 1), wn = w / WM;
  const int m0w = bx * (WM * 32) + wm * 32;
  const int n0  = by * ((4 / WM) * 64) + wn * 64;
  const int head = n0 >> 6;
  const int mt0 = m0w >> 4, nt0 = n0 >> 4;

  const float* pX[2];
  int rowmi[2];
  const ushort_t* pAh[2];
  #pragma unroll
  for (int mi = 0; mi < 2; ++mi) {
    if constexpr (TERMS == 3) {
      rowmi[mi] = (mt0 + mi) * 16 + (lane & 15);
      pX[mi] = Af32 + (size_t)rowmi[mi] * (KT * 32) + ((lane >> 4) << 3);
    } else {
      size_t fa = (size_t)(mt0 + mi) * KT;
      pAh[mi] = Ah + fa * 512 + (size_t)lane * 8;
    }
  }
  const ushort_t* pBh[4];
  const ushort_t* pBl[4];
  #pragma unroll
  for (int ni = 0; ni < 4; ++ni) {
    size_t fb = (size_t)(nt0 + ni) * KT;
    pBh[ni] = Bh + fb * 512 + (size_t)lane * 8;
    pBl[ni] = Bl + fb * 512 + (size_t)lane * 8;
  }

  f32x4 acc[2][4];
  #pragma unroll
  for (int mi = 0; mi < 2; ++mi)
    #pragma unroll
    for (int ni = 0; ni < 4; ++ni)
      acc[mi][ni] = (f32x4){0.f, 0.f, 0.f, 0.f};

  for (int kt = 0; kt < KT; ++kt) {
    const size_t ko = (size_t)kt * 512;
    bf16x8 ahf[2], alf[2], bhf[4], blf[4];
    #pragma unroll
    for (int mi = 0; mi < 2; ++mi) {
      if constexpr (TERMS == 3) {
        float v[8] = {0.f, 0.f, 0.f, 0.f, 0.f, 0.f, 0.f, 0.f};
        if (rowmi[mi] < M) {
          float4 a = *(const float4*)(pX[mi] + kt * 32);
          float4 b = *(const float4*)(pX[mi] + kt * 32 + 4);
          v[0] = a.x; v[1] = a.y; v[2] = a.z; v[3] = a.w;
          v[4] = b.x; v[5] = b.y; v[6] = b.z; v[7] = b.w;
        }
        union { ushort_t u[8]; bf16x8 f; } uh, ul;
        #pragma unroll
        for (int j = 0; j < 8; ++j) {
          uh.u[j] = f2bf(v[j]);
          ul.u[j] = f2bf(v[j] - bf2f(uh.u[j]));
        }
        ahf[mi] = uh.f;
        alf[mi] = ul.f;
      } else {
        ahf[mi] = *(const bf16x8*)(pAh[mi] + ko);
      }
    }
    #pragma unroll
    for (int ni = 0; ni < 4; ++ni) {
      bhf[ni] = *(const bf16x8*)(pBh[ni] + ko);
      blf[ni] = *(const bf16x8*)(pBl[ni] + ko);
    }
    #pragma unroll
    for (int mi = 0; mi < 2; ++mi)
      #pragma unroll
      for (int ni = 0; ni < 4; ++ni) {
        if constexpr (TERMS == 3)
          acc[mi][ni] = mfma16(alf[mi], bhf[ni], acc[mi][ni]);
        acc[mi][ni] = mfma16(ahf[mi], blf[ni], acc[mi][ni]);
        acc[mi][ni] = mfma16(ahf[mi], bhf[ni], acc[mi][ni]);
      }
  }

  // epilogue: per-row head dots + bf16 store
  // D mapping: col = (lane&15) + ni*16, row = (lane>>4)*4 + reg + mi*16
  const int c16 = lane & 15, q = lane >> 4;
  float sv[4], dv[4];
  #pragma unroll
  for (int ni = 0; ni < 4; ++ni) {
    sv[ni] = a_srcW[head * 64 + ni * 16 + c16];
    dv[ni] = a_dstW[head * 64 + ni * 16 + c16];
  }
  #pragma unroll
  for (int mi = 0; mi < 2; ++mi) {
    #pragma unroll
    for (int r = 0; r < 4; ++r) {
      int gr = m0w + mi * 16 + q * 4 + r;
      float ps = acc[mi][0][r] * sv[0] + acc[mi][1][r] * sv[1] +
                 acc[mi][2][r] * sv[2] + acc[mi][3][r] * sv[3];
      float pd = acc[mi][0][r] * dv[0] + acc[mi][1][r] * dv[1] +
                 acc[mi][2][r] * dv[2] + acc[mi][3][r] * dv[3];
      #pragma unroll
      for (int off = 1; off < 16; off <<= 1) {
        ps += __shfl_xor(ps, off);
        pd += __shfl_xor(pd, off);
      }
      if (gr < M) {
        #pragma unroll
        for (int ni = 0; ni < 4; ++ni)
          hb[(size_t)gr * Nn + n0 + ni * 16 + c16] = f2bf(acc[mi][ni][r]);
        if (c16 == 0) { as_[gr * H + head] = ps; ad_[gr * H + head] = pd; }
      }
    }
  }
}

__global__ __launch_bounds__(256)
void k_gemm1(const float* __restrict__ x,
             const ushort_t* __restrict__ B1h, const ushort_t* __restrict__ B1l,
             const float* __restrict__ as_w, const float* __restrict__ ad_w,
             ushort_t* __restrict__ h1b, float* __restrict__ as1,
             float* __restrict__ ad1, int M) {
  gemm_att_body<4, 3, 2>(blockIdx.x, blockIdx.y, x, nullptr, B1h, B1l,
                         as_w, ad_w, h1b, as1, ad1, M, 256, 4);
}

__global__ __launch_bounds__(256)
void k_gemm2(const ushort_t* __restrict__ A2h,
             const ushort_t* __restrict__ B2h, const ushort_t* __restrict__ B2l,
             const float* __restrict__ as_w, const float* __restrict__ ad_w,
             ushort_t* __restrict__ h2b, float* __restrict__ as2,
             float* __restrict__ ad2, int M) {
  gemm_att_body<8, 2, 4>(blockIdx.x, 0, nullptr, A2h, B2h, B2l,
                         as_w, ad_w, h2b, as2, ad2, M, 64, 1);
}

// ---------------- layer-1 aggregation (inline no-max weights, unroll-8) ----------------
// w = exp(leaky(as1[s]+ad1[wid])) computed in-kernel: as1 load is a broadcast
// across the 16 lanes of a head group. Output written in gemm2 A-frag layout.
__global__ void k_agg1(const ushort_t* __restrict__ h1b, const float* __restrict__ as1,
                       const float* __restrict__ ad1, const int* __restrict__ offs,
                       const int2* __restrict__ sed, const float* __restrict__ b1,
                       ushort_t* __restrict__ a2h, int N) {
  int gt = blockIdx.x * blockDim.x + threadIdx.x;
  int wid = gt >> 6, lane = gt & 63;
  if (wid >= N) return;
  int head = lane >> 4, sub = lane & 15, coff = sub << 2;
  int start = offs[wid], end = offs[wid + 1];
  float ad = ad1[wid * 4 + head];

  float denom = 0.f;
  float4 acc = make_float4(0.f, 0.f, 0.f, 0.f);
  int e = start;
  for (; e + 8 <= end; e += 8) {
    int s[8]; float w[8]; ushort4 g[8];
    #pragma unroll
    for (int j = 0; j < 8; ++j) s[j] = sed[e + j].x;
    #pragma unroll
    for (int j = 0; j < 8; ++j)
      g[j] = *(const ushort4*)(h1b + (size_t)s[j] * 256 + head * 64 + coff);
    #pragma unroll
    for (int j = 0; j < 8; ++j)
      w[j] = __expf(leaky(as1[s[j] * 4 + head] + ad));
    #pragma unroll
    for (int j = 0; j < 8; ++j) {
      denom += w[j];
      acc.x += w[j] * bf2f(g[j].x);
      acc.y += w[j] * bf2f(g[j].y);
      acc.z += w[j] * bf2f(g[j].z);
      acc.w += w[j] * bf2f(g[j].w);
    }
  }
  for (; e + 4 <= end; e += 4) {
    int s[4]; float w[4]; ushort4 g[4];
    #pragma unroll
    for (int j = 0; j < 4; ++j) s[j] = sed[e + j].x;
    #pragma unroll
    for (int j = 0; j < 4; ++j)
      g[j] = *(const ushort4*)(h1b + (size_t)s[j] * 256 + head * 64 + coff);
    #pragma unroll
    for (int j = 0; j < 4; ++j)
      w[j] = __expf(leaky(as1[s[j] * 4 + head] + ad));
    #pragma unroll
    for (int j = 0; j < 4; ++j) {
      denom += w[j];
      acc.x += w[j] * bf2f(g[j].x);
      acc.y += w[j] * bf2f(g[j].y);
      acc.z += w[j] * bf2f(g[j].z);
      acc.w += w[j] * bf2f(g[j].w);
    }
  }
  for (; e < end; ++e) {
    int s = sed[e].x;
    float w = __expf(leaky(as1[s * 4 + head] + ad));
    ushort4 g = *(const ushort4*)(h1b + (size_t)s * 256 + head * 64 + coff);
    denom += w;
    acc.x += w * bf2f(g.x); acc.y += w * bf2f(g.y);
    acc.z += w * bf2f(g.z); acc.w += w * bf2f(g.w);
  }
  float inv = 1.f / denom;
  float4 bv = *(const float4*)(b1 + head * 64 + coff);
  // packed write into gemm2 A-fragment layout
  int c0 = head * 64 + coff;
  int fa = (wid >> 4) * 8 + (c0 >> 5);
  int fl = (wid & 15) | (((c0 >> 3) & 3) << 4);
  size_t addr = ((size_t)fa * 64 + fl) * 8 + (c0 & 7);
  ushort4 o;
  o.x = f2bf(fmaxf(acc.x * inv + bv.x, 0.f));
  o.y = f2bf(fmaxf(acc.y * inv + bv.y, 0.f));
  o.z = f2bf(fmaxf(acc.z * inv + bv.z, 0.f));
  o.w = f2bf(fmaxf(acc.w * inv + bv.w, 0.f));
  *(ushort4*)(a2h + addr) = o;
}

// ---------------- layer-2 aggregation: half-wave pairing, inline weights ----------------
__global__ void k_agg2(const ushort_t* __restrict__ h2b, const float* __restrict__ as2,
                       const float* __restrict__ ad2, const int* __restrict__ offs,
                       const int2* __restrict__ sed, const float* __restrict__ b2,
                       float* __restrict__ hfin, int N) {
  int gt = blockIdx.x * blockDim.x + threadIdx.x;
  int wid = gt >> 6, lane = gt & 63;
  if (wid >= N) return;
  int half = lane >> 5, li = lane & 31;
  int start = offs[wid], end = offs[wid + 1];
  float ad = ad2[wid];

  float dn = 0.f, acc0 = 0.f, acc1 = 0.f;
  int e = start;
  for (; e + 8 <= end; e += 8) {
    int e0 = e + half, e1 = e + 2 + half, e2 = e + 4 + half, e3 = e + 6 + half;
    int s0 = sed[e0].x, s1 = sed[e1].x, s2 = sed[e2].x, s3 = sed[e3].x;
    unsigned g0 = *(const unsigned*)(h2b + (size_t)s0 * 64 + li * 2);
    unsigned g1 = *(const unsigned*)(h2b + (size_t)s1 * 64 + li * 2);
    unsigned g2 = *(const unsigned*)(h2b + (size_t)s2 * 64 + li * 2);
    unsigned g3 = *(const unsigned*)(h2b + (size_t)s3 * 64 + li * 2);
    float wa = __expf(leaky(as2[s0] + ad));
    float wb = __expf(leaky(as2[s1] + ad));
    float wc = __expf(leaky(as2[s2] + ad));
    float wd = __expf(leaky(as2[s3] + ad));
    dn += (wa + wb) + (wc + wd);
    acc0 += wa * __uint_as_float(g0 << 16) + wb * __uint_as_float(g1 << 16)
          + wc * __uint_as_float(g2 << 16) + wd * __uint_as_float(g3 << 16);
    acc1 += wa * __uint_as_float(g0 & 0xffff0000u) + wb * __uint_as_float(g1 & 0xffff0000u)
          + wc * __uint_as_float(g2 & 0xffff0000u) + wd * __uint_as_float(g3 & 0xffff0000u);
  }
  for (; e + 2 <= end; e += 2) {
    int e0 = e + half;
    int s0 = sed[e0].x;
    float wa = __expf(leaky(as2[s0] + ad));
    unsigned g0 = *(const unsigned*)(h2b + (size_t)s0 * 64 + li * 2);
    dn += wa;
    acc0 += wa * __uint_as_float(g0 << 16);
    acc1 += wa * __uint_as_float(g0 & 0xffff0000u);
  }
  if (e < end && half == 0) {   // odd leftover edge
    int s0 = sed[e].x;
    float wa = __expf(leaky(as2[s0] + ad));
    unsigned g0 = *(const unsigned*)(h2b + (size_t)s0 * 64 + li * 2);
    dn += wa;
    acc0 += wa * __uint_as_float(g0 << 16);
    acc1 += wa * __uint_as_float(g0 & 0xffff0000u);
  }
  acc0 += __shfl_xor(acc0, 32);
  acc1 += __shfl_xor(acc1, 32);
  dn   += __shfl_xor(dn, 32);
  if (half == 0) {
    float inv = 1.f / dn;
    float2 bv = *(const float2*)(b2 + li * 2);
    float2 o;
    o.x = acc0 * inv + bv.x;
    o.y = acc1 * inv + bv.y;
    *(float2*)(hfin + (size_t)wid * 64 + li * 2) = o;
  }
}

// ---------------- global mean pool (batch is sorted) ----------------
__global__ void k_pool(const float* __restrict__ hfin, const int* __restrict__ gstart,
                       float* __restrict__ out) {
  int g = blockIdx.x;
  int c = threadIdx.x & 63, r = threadIdx.x >> 6;
  int start = gstart[g], cnt = gstart[g + 1] - start;
  float acc = 0.f;
  for (int i = r; i < cnt; i += 4)
    acc += hfin[(size_t)(start + i) * 64 + c];
  __shared__ float red[256];
  red[threadIdx.x] = acc;
  __syncthreads();
  if (r == 0)
    out[g * 64 + c] = (red[c] + red[64 + c] + red[128 + c] + red[192 + c]) /
                      fmaxf((float)cnt, 1.f);
}

// ---------------- launcher ----------------
extern "C" void kernel_launch(void* const* d_in, const int* in_sizes, int n_in,
                              void* d_out, int out_size, void* d_ws, size_t ws_size,
                              hipStream_t stream) {
  const float* x        = (const float*)d_in[0];
  const int*   ei       = (const int*)d_in[1];
  const int*   batch    = (const int*)d_in[2];
  const float* W1       = (const float*)d_in[3];
  const float* att_src1 = (const float*)d_in[4];
  const float* att_dst1 = (const float*)d_in[5];
  const float* b1       = (const float*)d_in[6];
  const float* W2       = (const float*)d_in[7];
  const float* att_src2 = (const float*)d_in[8];
  const float* att_dst2 = (const float*)d_in[9];
  const float* b2       = (const float*)d_in[10];
  float* out = (float*)d_out;

  const int N = in_sizes[0] / 128;   // 50000
  const int E = in_sizes[1] / 2;     // 800000
  const int EE = E + N;
  const int* esrc = ei;
  const int* edst = ei + E;

  const int GB2 = (N + 127) / 128;       // gemm2 blocks (128 rows)
  const int GB1 = GB2 * 2;               // gemm1 x-blocks (64 rows)
  const int MF  = GB2 * 8;               // padded m-frags (rows/16)
  const int NB  = (N + 1023) / 1024;     // scan blocks (<= 64)
  const int HB  = (E + 255) / 256;       // hist blocks
  const int GBB = (N + 255) / 256;       // gbounds blocks

  // workspace carve (256B aligned)
  char* p = (char*)d_ws;
  auto alloc = [&](size_t bytes) -> void* {
    void* r = (void*)p;
    p += (bytes + 255) & ~(size_t)255;
    return r;
  };
  ushort_t* A2h  = (ushort_t*)alloc((size_t)MF * 8 * 64 * 16);  // written by k_agg1
  ushort_t* B1h  = (ushort_t*)alloc((size_t)16 * 4 * 64 * 16);
  ushort_t* B1l  = (ushort_t*)alloc((size_t)16 * 4 * 64 * 16);
  ushort_t* B2h  = (ushort_t*)alloc((size_t)4 * 8 * 64 * 16);
  ushort_t* B2l  = (ushort_t*)alloc((size_t)4 * 8 * 64 * 16);
  ushort_t* h1b  = (ushort_t*)alloc((size_t)N * 256 * 2);
  ushort_t* h2b  = (ushort_t*)alloc((size_t)N * 64 * 2);
  float*    hfin = (float*)alloc((size_t)N * 64 * 4);
  float*    as1  = (float*)alloc((size_t)N * 4 * 4);
  float*    ad1  = (float*)alloc((size_t)N * 4 * 4);
  float*    as2  = (float*)alloc((size_t)N * 4);
  float*    ad2  = (float*)alloc((size_t)N * 4);
  int*  deg     = (int*)alloc((size_t)N * 4);
  int*  offsets = (int*)alloc((size_t)(N + 1) * 4);
  int*  cursor  = (int*)alloc((size_t)N * 4);
  int2* sed     = (int2*)alloc((size_t)EE * 8);
  int*  bsum    = (int*)alloc(64 * 4);
  int*  bbase   = (int*)alloc(64 * 4);
  int*  gstart  = (int*)alloc(65 * 4);

  // --- zero degree array (async, capture-safe) ---
  hipMemsetAsync(deg, 0, (size_t)N * 4, stream);

  // --- fused setup: hist | gbounds | packB ---
  k_setup<<<HB + GBB + 24, 256, 0, stream>>>(edst, E, deg, batch, N, 64, gstart,
                                             W1, W2, B1h, B1l, B2h, B2l, HB, GBB);

  // --- scan over deg+1 ---
  k_scan_bsum<<<NB, 1024, 0, stream>>>(deg, N, bsum);
  k_scan_bbase<<<1, 64, 0, stream>>>(bsum, NB, bbase, offsets, N);
  k_scan_final<<<NB, 1024, 0, stream>>>(deg, N, bbase, offsets, cursor);

  // --- scatter (standalone; atomic-latency-bound, wants max breadth) ---
  k_scatter<<<1024, 256, 0, stream>>>(esrc, edst, E, N, cursor, sed);

  // --- layer 1: MFMA GEMM (direct f32 A) + fused logits, then aggregation ---
  k_gemm1<<<dim3(GB1, 2), 256, 0, stream>>>(x, B1h, B1l, att_src1, att_dst1,
                                            h1b, as1, ad1, N);
  int wave_blocks = (N * 64 + 255) / 256;
  k_agg1<<<wave_blocks, 256, 0, stream>>>(h1b, as1, ad1, offsets, sed, b1, A2h, N);

  // --- layer 2 ---
  k_gemm2<<<GB2, 256, 0, stream>>>(A2h, B2h, B2l, att_src2, att_dst2,
                                   h2b, as2, ad2, N);
  k_agg2<<<wave_blocks, 256, 0, stream>>>(h2b, as2, ad2, offsets, sed, b2, hfin, N);

  // --- global mean pool ---
  k_pool<<<64, 256, 0, stream>>>(hfin, gstart, out);
}

// Round 14
// 292.131 us; speedup vs baseline: 1.0855x; 1.0359x over previous
//
#include <hip/hip_runtime.h>
#include <math.h>

// ---------------- problem constants (match reference) ----------------
// N=50000, F_IN=128, HID=64, HEADS1=4 (C1=256), NUM_GRAPHS=64, slope=0.2

typedef unsigned short ushort_t;
typedef __bf16 bf16x8 __attribute__((ext_vector_type(8)));
typedef float  f32x4  __attribute__((ext_vector_type(4)));

__device__ inline float bf2f(ushort_t u) { return __uint_as_float((unsigned)u << 16); }
__device__ inline ushort_t f2bf(float x) {            // round-to-nearest-even
  unsigned b = __float_as_uint(x);
  return (ushort_t)((b + 0x7fff + ((b >> 16) & 1)) >> 16);
}
__device__ inline float leaky(float v) { return (v > 0.f) ? v : 0.2f * v; }

__device__ inline f32x4 mfma16(bf16x8 a, bf16x8 b, f32x4 c) {
  return __builtin_amdgcn_mfma_f32_16x16x32_bf16(a, b, c, 0, 0, 0);
}

// ---------------- B-operand pack helper ----------------
// frag layout: frag-lane fl = frag*64+lane; lane l holds j=0..7 with
// col=(l&15), k = kt*32 + (l>>4)*8 + j. A uses same k-slot convention.
__device__ inline void packB_one(const float* __restrict__ B, ushort_t* __restrict__ bh,
                                 ushort_t* __restrict__ bl, int K, int Nn, int t) {
  int KT = K >> 5;
  int l = t & 63, fb = t >> 6;
  int nt = fb / KT, kt = fb - nt * KT;
  int col = nt * 16 + (l & 15);
  int k0 = kt * 32 + (l >> 4) * 8;
  ushort_t h[8], lo[8];
  #pragma unroll
  for (int j = 0; j < 8; ++j) {
    float v = B[(size_t)(k0 + j) * Nn + col];
    h[j] = f2bf(v);
    lo[j] = f2bf(v - bf2f(h[j]));
  }
  size_t o = (size_t)t * 8;
  *(ushort4*)(bh + o)     = make_ushort4(h[0], h[1], h[2], h[3]);
  *(ushort4*)(bh + o + 4) = make_ushort4(h[4], h[5], h[6], h[7]);
  *(ushort4*)(bl + o)     = make_ushort4(lo[0], lo[1], lo[2], lo[3]);
  *(ushort4*)(bl + o + 4) = make_ushort4(lo[4], lo[5], lo[6], lo[7]);
}

// ---------------- fused setup: hist (real edges only) | gbounds | packB ----------------
// deg zeroed beforehand (hipMemsetAsync). Self-loops NOT counted; scan adds +1/node.
__global__ void k_setup(const int* __restrict__ edst, int E, int* __restrict__ deg,
                        const int* __restrict__ batch, int N, int G,
                        int* __restrict__ gstart,
                        const float* __restrict__ W1, const float* __restrict__ W2,
                        ushort_t* __restrict__ B1h, ushort_t* __restrict__ B1l,
                        ushort_t* __restrict__ B2h, ushort_t* __restrict__ B2l,
                        int HB, int GBB) {
  int b = blockIdx.x, tid = threadIdx.x;
  if (b < HB) {
    int i = b * 256 + tid;
    if (i < E) atomicAdd(&deg[edst[i]], 1);
  } else if (b < HB + GBB) {
    int i = (b - HB) * 256 + tid;
    if (i < N) {
      int bb = batch[i];
      int bp = (i == 0) ? -1 : batch[i - 1];
      for (int g = bp + 1; g <= bb; ++g) gstart[g] = i;
      if (i == N - 1)
        for (int g = bb + 1; g <= G; ++g) gstart[g] = N;
    }
  } else {
    int t = (b - HB - GBB) * 256 + tid;
    if (t < 4096) packB_one(W1, B1h, B1l, 128, 256, t);            // 16 nf x 4 kt
    else if (t < 6144) packB_one(W2, B2h, B2l, 256, 64, t - 4096); // 4 nf x 8 kt
  }
}

// ---------------- 3-pass multi-block exclusive scan over (deg[i]+1) ----------------
__global__ void k_scan_bsum(const int* __restrict__ deg, int n, int* __restrict__ bsum) {
  __shared__ int ws[16];
  int tid = threadIdx.x, lane = tid & 63, wv = tid >> 6;
  int i = blockIdx.x * 1024 + tid;
  int v = (i < n) ? deg[i] + 1 : 0;
  #pragma unroll
  for (int off = 1; off < 64; off <<= 1) v += __shfl_xor(v, off);
  if (lane == 0) ws[wv] = v;
  __syncthreads();
  if (tid < 16) {
    int s = ws[tid];
    #pragma unroll
    for (int off = 1; off < 16; off <<= 1) s += __shfl_xor(s, off);
    if (tid == 0) bsum[blockIdx.x] = s;
  }
}

__global__ void k_scan_bbase(const int* __restrict__ bsum, int nb,
                             int* __restrict__ bbase, int* __restrict__ offsets, int n) {
  int lane = threadIdx.x & 63;
  int v = (lane < nb) ? bsum[lane] : 0;
  int x = v;
  #pragma unroll
  for (int off = 1; off < 64; off <<= 1) {
    int t = __shfl_up(x, off);
    if (lane >= off) x += t;
  }
  if (lane < nb) bbase[lane] = x - v;
  if (lane == nb - 1) offsets[n] = x;
}

__global__ void k_scan_final(const int* __restrict__ deg, int n,
                             const int* __restrict__ bbase,
                             int* __restrict__ offsets, int* __restrict__ cursor) {
  __shared__ int wsum[16];
  int tid = threadIdx.x, lane = tid & 63, wv = tid >> 6;
  int i = blockIdx.x * 1024 + tid;
  int v = (i < n) ? deg[i] + 1 : 0;
  int x = v;
  #pragma unroll
  for (int off = 1; off < 64; off <<= 1) {
    int t = __shfl_up(x, off);
    if (lane >= off) x += t;
  }
  if (lane == 63) wsum[wv] = x;
  __syncthreads();
  if (wv == 0 && lane < 16) {
    int s = wsum[lane];
    #pragma unroll
    for (int off = 1; off < 16; off <<= 1) {
      int t = __shfl_up(s, off);
      if (lane >= off) s += t;
    }
    wsum[lane] = s;
  }
  __syncthreads();
  int wbase = (wv == 0) ? 0 : wsum[wv - 1];
  int incl = bbase[blockIdx.x] + wbase + x;
  if (i < n) { int o = incl - v; offsets[i] = o; cursor[i] = o; }
}

// ---------------- scatter: 1 edge/thread, src-only (4B) payload ----------------
__global__ void k_scatter(const int* __restrict__ esrc, const int* __restrict__ edst,
                          int E, int N, int* __restrict__ cursor,
                          int* __restrict__ ssrc) {
  int i = blockIdx.x * blockDim.x + threadIdx.x;
  int EE = E + N;
  if (i >= EE) return;
  int d, s;
  if (i < E) { d = edst[i]; s = esrc[i]; }
  else       { d = i - E;   s = i - E;   }
  int pos = atomicAdd(&cursor[d], 1);
  ssrc[pos] = s;
}

// ---------------- MFMA GEMM + fused attention logits (device body) ----------------
// TERMS==3: A loaded DIRECTLY from f32 (in-register hi/lo split), 3-term product.
// TERMS==2: A from packed bf16 frags (Ah), 2-term product.
template<int KT, int TERMS, int WM>
__device__ void gemm_att_body(int bx, int by,
                              const float* __restrict__ Af32, const ushort_t* __restrict__ Ah,
                              const ushort_t* __restrict__ Bh, const ushort_t* __restrict__ Bl,
                              const float* __restrict__ a_srcW, const float* __restrict__ a_dstW,
                              ushort_t* __restrict__ hb, float* __restrict__ as_,
                              float* __restrict__ ad_, int M, int Nn, int H) {
  const int tid = threadIdx.x;
  const int w = tid >> 6, lane = tid & 63;
  const int wm = w & (WM - 1), wn = w / WM;
  const int m0w = bx * (WM * 32) + wm * 32;
  const int n0  = by * ((4 / WM) * 64) + wn * 64;
  const int head = n0 >> 6;
  const int mt0 = m0w >> 4, nt0 = n0 >> 4;

  const float* pX[2];
  int rowmi[2];
  const ushort_t* pAh[2];
  #pragma unroll
  for (int mi = 0; mi < 2; ++mi) {
    if constexpr (TERMS == 3) {
      rowmi[mi] = (mt0 + mi) * 16 + (lane & 15);
      pX[mi] = Af32 + (size_t)rowmi[mi] * (KT * 32) + ((lane >> 4) << 3);
    } else {
      size_t fa = (size_t)(mt0 + mi) * KT;
      pAh[mi] = Ah + fa * 512 + (size_t)lane * 8;
    }
  }
  const ushort_t* pBh[4];
  const ushort_t* pBl[4];
  #pragma unroll
  for (int ni = 0; ni < 4; ++ni) {
    size_t fb = (size_t)(nt0 + ni) * KT;
    pBh[ni] = Bh + fb * 512 + (size_t)lane * 8;
    pBl[ni] = Bl + fb * 512 + (size_t)lane * 8;
  }

  f32x4 acc[2][4];
  #pragma unroll
  for (int mi = 0; mi < 2; ++mi)
    #pragma unroll
    for (int ni = 0; ni < 4; ++ni)
      acc[mi][ni] = (f32x4){0.f, 0.f, 0.f, 0.f};

  for (int kt = 0; kt < KT; ++kt) {
    const size_t ko = (size_t)kt * 512;
    bf16x8 ahf[2], alf[2], bhf[4], blf[4];
    #pragma unroll
    for (int mi = 0; mi < 2; ++mi) {
      if constexpr (TERMS == 3) {
        float v[8] = {0.f, 0.f, 0.f, 0.f, 0.f, 0.f, 0.f, 0.f};
        if (rowmi[mi] < M) {
          float4 a = *(const float4*)(pX[mi] + kt * 32);
          float4 b = *(const float4*)(pX[mi] + kt * 32 + 4);
          v[0] = a.x; v[1] = a.y; v[2] = a.z; v[3] = a.w;
          v[4] = b.x; v[5] = b.y; v[6] = b.z; v[7] = b.w;
        }
        union { ushort_t u[8]; bf16x8 f; } uh, ul;
        #pragma unroll
        for (int j = 0; j < 8; ++j) {
          uh.u[j] = f2bf(v[j]);
          ul.u[j] = f2bf(v[j] - bf2f(uh.u[j]));
        }
        ahf[mi] = uh.f;
        alf[mi] = ul.f;
      } else {
        ahf[mi] = *(const bf16x8*)(pAh[mi] + ko);
      }
    }
    #pragma unroll
    for (int ni = 0; ni < 4; ++ni) {
      bhf[ni] = *(const bf16x8*)(pBh[ni] + ko);
      blf[ni] = *(const bf16x8*)(pBl[ni] + ko);
    }
    #pragma unroll
    for (int mi = 0; mi < 2; ++mi)
      #pragma unroll
      for (int ni = 0; ni < 4; ++ni) {
        if constexpr (TERMS == 3)
          acc[mi][ni] = mfma16(alf[mi], bhf[ni], acc[mi][ni]);
        acc[mi][ni] = mfma16(ahf[mi], blf[ni], acc[mi][ni]);
        acc[mi][ni] = mfma16(ahf[mi], bhf[ni], acc[mi][ni]);
      }
  }

  // epilogue: per-row head dots + bf16 store
  // D mapping: col = (lane&15) + ni*16, row = (lane>>4)*4 + reg + mi*16
  const int c16 = lane & 15, q = lane >> 4;
  float sv[4], dv[4];
  #pragma unroll
  for (int ni = 0; ni < 4; ++ni) {
    sv[ni] = a_srcW[head * 64 + ni * 16 + c16];
    dv[ni] = a_dstW[head * 64 + ni * 16 + c16];
  }
  #pragma unroll
  for (int mi = 0; mi < 2; ++mi) {
    #pragma unroll
    for (int r = 0; r < 4; ++r) {
      int gr = m0w + mi * 16 + q * 4 + r;
      float ps = acc[mi][0][r] * sv[0] + acc[mi][1][r] * sv[1] +
                 acc[mi][2][r] * sv[2] + acc[mi][3][r] * sv[3];
      float pd = acc[mi][0][r] * dv[0] + acc[mi][1][r] * dv[1] +
                 acc[mi][2][r] * dv[2] + acc[mi][3][r] * dv[3];
      #pragma unroll
      for (int off = 1; off < 16; off <<= 1) {
        ps += __shfl_xor(ps, off);
        pd += __shfl_xor(pd, off);
      }
      if (gr < M) {
        #pragma unroll
        for (int ni = 0; ni < 4; ++ni)
          hb[(size_t)gr * Nn + n0 + ni * 16 + c16] = f2bf(acc[mi][ni][r]);
        if (c16 == 0) { as_[gr * H + head] = ps; ad_[gr * H + head] = pd; }
      }
    }
  }
}

__global__ __launch_bounds__(256)
void k_gemm1(const float* __restrict__ x,
             const ushort_t* __restrict__ B1h, const ushort_t* __restrict__ B1l,
             const float* __restrict__ as_w, const float* __restrict__ ad_w,
             ushort_t* __restrict__ h1b, float* __restrict__ as1,
             float* __restrict__ ad1, int M) {
  gemm_att_body<4, 3, 2>(blockIdx.x, blockIdx.y, x, nullptr, B1h, B1l,
                         as_w, ad_w, h1b, as1, ad1, M, 256, 4);
}

__global__ __launch_bounds__(256)
void k_gemm2(const ushort_t* __restrict__ A2h,
             const ushort_t* __restrict__ B2h, const ushort_t* __restrict__ B2l,
             const float* __restrict__ as_w, const float* __restrict__ ad_w,
             ushort_t* __restrict__ h2b, float* __restrict__ as2,
             float* __restrict__ ad2, int M) {
  gemm_att_body<8, 2, 4>(blockIdx.x, 0, nullptr, A2h, B2h, B2l,
                         as_w, ad_w, h2b, as2, ad2, M, 64, 1);
}

// ---------------- layer-1 aggregation (inline no-max weights, unroll-8) ----------------
// w = exp(leaky(as1[s]+ad1[wid])) computed in-kernel: as1 load is a broadcast
// across the 16 lanes of a head group. Output written in gemm2 A-frag layout.
__global__ void k_agg1(const ushort_t* __restrict__ h1b, const float* __restrict__ as1,
                       const float* __restrict__ ad1, const int* __restrict__ offs,
                       const int* __restrict__ ssrc, const float* __restrict__ b1,
                       ushort_t* __restrict__ a2h, int N) {
  int gt = blockIdx.x * blockDim.x + threadIdx.x;
  int wid = gt >> 6, lane = gt & 63;
  if (wid >= N) return;
  int head = lane >> 4, sub = lane & 15, coff = sub << 2;
  int start = offs[wid], end = offs[wid + 1];
  float ad = ad1[wid * 4 + head];

  float denom = 0.f;
  float4 acc = make_float4(0.f, 0.f, 0.f, 0.f);
  int e = start;
  for (; e + 8 <= end; e += 8) {
    int s[8]; float w[8]; ushort4 g[8];
    #pragma unroll
    for (int j = 0; j < 8; ++j) s[j] = ssrc[e + j];
    #pragma unroll
    for (int j = 0; j < 8; ++j)
      g[j] = *(const ushort4*)(h1b + (size_t)s[j] * 256 + head * 64 + coff);
    #pragma unroll
    for (int j = 0; j < 8; ++j)
      w[j] = __expf(leaky(as1[s[j] * 4 + head] + ad));
    #pragma unroll
    for (int j = 0; j < 8; ++j) {
      denom += w[j];
      acc.x += w[j] * bf2f(g[j].x);
      acc.y += w[j] * bf2f(g[j].y);
      acc.z += w[j] * bf2f(g[j].z);
      acc.w += w[j] * bf2f(g[j].w);
    }
  }
  for (; e + 4 <= end; e += 4) {
    int s[4]; float w[4]; ushort4 g[4];
    #pragma unroll
    for (int j = 0; j < 4; ++j) s[j] = ssrc[e + j];
    #pragma unroll
    for (int j = 0; j < 4; ++j)
      g[j] = *(const ushort4*)(h1b + (size_t)s[j] * 256 + head * 64 + coff);
    #pragma unroll
    for (int j = 0; j < 4; ++j)
      w[j] = __expf(leaky(as1[s[j] * 4 + head] + ad));
    #pragma unroll
    for (int j = 0; j < 4; ++j) {
      denom += w[j];
      acc.x += w[j] * bf2f(g[j].x);
      acc.y += w[j] * bf2f(g[j].y);
      acc.z += w[j] * bf2f(g[j].z);
      acc.w += w[j] * bf2f(g[j].w);
    }
  }
  for (; e < end; ++e) {
    int s = ssrc[e];
    float w = __expf(leaky(as1[s * 4 + head] + ad));
    ushort4 g = *(const ushort4*)(h1b + (size_t)s * 256 + head * 64 + coff);
    denom += w;
    acc.x += w * bf2f(g.x); acc.y += w * bf2f(g.y);
    acc.z += w * bf2f(g.z); acc.w += w * bf2f(g.w);
  }
  float inv = 1.f / denom;
  float4 bv = *(const float4*)(b1 + head * 64 + coff);
  // packed write into gemm2 A-fragment layout
  int c0 = head * 64 + coff;
  int fa = (wid >> 4) * 8 + (c0 >> 5);
  int fl = (wid & 15) | (((c0 >> 3) & 3) << 4);
  size_t addr = ((size_t)fa * 64 + fl) * 8 + (c0 & 7);
  ushort4 o;
  o.x = f2bf(fmaxf(acc.x * inv + bv.x, 0.f));
  o.y = f2bf(fmaxf(acc.y * inv + bv.y, 0.f));
  o.z = f2bf(fmaxf(acc.z * inv + bv.z, 0.f));
  o.w = f2bf(fmaxf(acc.w * inv + bv.w, 0.f));
  *(ushort4*)(a2h + addr) = o;
}

// ---------------- layer-2 aggregation: half-wave pairing, inline weights ----------------
__global__ void k_agg2(const ushort_t* __restrict__ h2b, const float* __restrict__ as2,
                       const float* __restrict__ ad2, const int* __restrict__ offs,
                       const int* __restrict__ ssrc, const float* __restrict__ b2,
                       float* __restrict__ hfin, int N) {
  int gt = blockIdx.x * blockDim.x + threadIdx.x;
  int wid = gt >> 6, lane = gt & 63;
  if (wid >= N) return;
  int half = lane >> 5, li = lane & 31;
  int start = offs[wid], end = offs[wid + 1];
  float ad = ad2[wid];

  float dn = 0.f, acc0 = 0.f, acc1 = 0.f;
  int e = start;
  for (; e + 8 <= end; e += 8) {
    int e0 = e + half, e1 = e + 2 + half, e2 = e + 4 + half, e3 = e + 6 + half;
    int s0 = ssrc[e0], s1 = ssrc[e1], s2 = ssrc[e2], s3 = ssrc[e3];
    unsigned g0 = *(const unsigned*)(h2b + (size_t)s0 * 64 + li * 2);
    unsigned g1 = *(const unsigned*)(h2b + (size_t)s1 * 64 + li * 2);
    unsigned g2 = *(const unsigned*)(h2b + (size_t)s2 * 64 + li * 2);
    unsigned g3 = *(const unsigned*)(h2b + (size_t)s3 * 64 + li * 2);
    float wa = __expf(leaky(as2[s0] + ad));
    float wb = __expf(leaky(as2[s1] + ad));
    float wc = __expf(leaky(as2[s2] + ad));
    float wd = __expf(leaky(as2[s3] + ad));
    dn += (wa + wb) + (wc + wd);
    acc0 += wa * __uint_as_float(g0 << 16) + wb * __uint_as_float(g1 << 16)
          + wc * __uint_as_float(g2 << 16) + wd * __uint_as_float(g3 << 16);
    acc1 += wa * __uint_as_float(g0 & 0xffff0000u) + wb * __uint_as_float(g1 & 0xffff0000u)
          + wc * __uint_as_float(g2 & 0xffff0000u) + wd * __uint_as_float(g3 & 0xffff0000u);
  }
  for (; e + 2 <= end; e += 2) {
    int e0 = e + half;
    int s0 = ssrc[e0];
    float wa = __expf(leaky(as2[s0] + ad));
    unsigned g0 = *(const unsigned*)(h2b + (size_t)s0 * 64 + li * 2);
    dn += wa;
    acc0 += wa * __uint_as_float(g0 << 16);
    acc1 += wa * __uint_as_float(g0 & 0xffff0000u);
  }
  if (e < end && half == 0) {   // odd leftover edge
    int s0 = ssrc[e];
    float wa = __expf(leaky(as2[s0] + ad));
    unsigned g0 = *(const unsigned*)(h2b + (size_t)s0 * 64 + li * 2);
    dn += wa;
    acc0 += wa * __uint_as_float(g0 << 16);
    acc1 += wa * __uint_as_float(g0 & 0xffff0000u);
  }
  acc0 += __shfl_xor(acc0, 32);
  acc1 += __shfl_xor(acc1, 32);
  dn   += __shfl_xor(dn, 32);
  if (half == 0) {
    float inv = 1.f / dn;
    float2 bv = *(const float2*)(b2 + li * 2);
    float2 o;
    o.x = acc0 * inv + bv.x;
    o.y = acc1 * inv + bv.y;
    *(float2*)(hfin + (size_t)wid * 64 + li * 2) = o;
  }
}

// ---------------- global mean pool (batch is sorted) ----------------
__global__ void k_pool(const float* __restrict__ hfin, const int* __restrict__ gstart,
                       float* __restrict__ out) {
  int g = blockIdx.x;
  int c = threadIdx.x & 63, r = threadIdx.x >> 6;
  int start = gstart[g], cnt = gstart[g + 1] - start;
  float acc = 0.f;
  for (int i = r; i < cnt; i += 4)
    acc += hfin[(size_t)(start + i) * 64 + c];
  __shared__ float red[256];
  red[threadIdx.x] = acc;
  __syncthreads();
  if (r == 0)
    out[g * 64 + c] = (red[c] + red[64 + c] + red[128 + c] + red[192 + c]) /
                      fmaxf((float)cnt, 1.f);
}

// ---------------- launcher ----------------
extern "C" void kernel_launch(void* const* d_in, const int* in_sizes, int n_in,
                              void* d_out, int out_size, void* d_ws, size_t ws_size,
                              hipStream_t stream) {
  const float* x        = (const float*)d_in[0];
  const int*   ei       = (const int*)d_in[1];
  const int*   batch    = (const int*)d_in[2];
  const float* W1       = (const float*)d_in[3];
  const float* att_src1 = (const float*)d_in[4];
  const float* att_dst1 = (const float*)d_in[5];
  const float* b1       = (const float*)d_in[6];
  const float* W2       = (const float*)d_in[7];
  const float* att_src2 = (const float*)d_in[8];
  const float* att_dst2 = (const float*)d_in[9];
  const float* b2       = (const float*)d_in[10];
  float* out = (float*)d_out;

  const int N = in_sizes[0] / 128;   // 50000
  const int E = in_sizes[1] / 2;     // 800000
  const int EE = E + N;
  const int* esrc = ei;
  const int* edst = ei + E;

  const int GB2 = (N + 127) / 128;       // gemm2 blocks (128 rows)
  const int GB1 = GB2 * 2;               // gemm1 x-blocks (64 rows)
  const int MF  = GB2 * 8;               // padded m-frags (rows/16)
  const int NB  = (N + 1023) / 1024;     // scan blocks (<= 64)
  const int HB  = (E + 255) / 256;       // hist blocks
  const int GBB = (N + 255) / 256;       // gbounds blocks
  const int SCB = (EE + 255) / 256;      // scatter blocks (1 edge/thread)

  // workspace carve (256B aligned)
  char* p = (char*)d_ws;
  auto alloc = [&](size_t bytes) -> void* {
    void* r = (void*)p;
    p += (bytes + 255) & ~(size_t)255;
    return r;
  };
  ushort_t* A2h  = (ushort_t*)alloc((size_t)MF * 8 * 64 * 16);  // written by k_agg1
  ushort_t* B1h  = (ushort_t*)alloc((size_t)16 * 4 * 64 * 16);
  ushort_t* B1l  = (ushort_t*)alloc((size_t)16 * 4 * 64 * 16);
  ushort_t* B2h  = (ushort_t*)alloc((size_t)4 * 8 * 64 * 16);
  ushort_t* B2l  = (ushort_t*)alloc((size_t)4 * 8 * 64 * 16);
  ushort_t* h1b  = (ushort_t*)alloc((size_t)N * 256 * 2);
  ushort_t* h2b  = (ushort_t*)alloc((size_t)N * 64 * 2);
  float*    hfin = (float*)alloc((size_t)N * 64 * 4);
  float*    as1  = (float*)alloc((size_t)N * 4 * 4);
  float*    ad1  = (float*)alloc((size_t)N * 4 * 4);
  float*    as2  = (float*)alloc((size_t)N * 4);
  float*    ad2  = (float*)alloc((size_t)N * 4);
  int*  deg     = (int*)alloc((size_t)N * 4);
  int*  offsets = (int*)alloc((size_t)(N + 1) * 4);
  int*  cursor  = (int*)alloc((size_t)N * 4);
  int*  ssrc    = (int*)alloc((size_t)EE * 4);
  int*  bsum    = (int*)alloc(64 * 4);
  int*  bbase   = (int*)alloc(64 * 4);
  int*  gstart  = (int*)alloc(65 * 4);

  // --- zero degree array (async, capture-safe) ---
  hipMemsetAsync(deg, 0, (size_t)N * 4, stream);

  // --- fused setup: hist | gbounds | packB ---
  k_setup<<<HB + GBB + 24, 256, 0, stream>>>(edst, E, deg, batch, N, 64, gstart,
                                             W1, W2, B1h, B1l, B2h, B2l, HB, GBB);

  // --- scan over deg+1 ---
  k_scan_bsum<<<NB, 1024, 0, stream>>>(deg, N, bsum);
  k_scan_bbase<<<1, 64, 0, stream>>>(bsum, NB, bbase, offsets, N);
  k_scan_final<<<NB, 1024, 0, stream>>>(deg, N, bbase, offsets, cursor);

  // --- scatter: 1 edge/thread for max atomic concurrency ---
  k_scatter<<<SCB, 256, 0, stream>>>(esrc, edst, E, N, cursor, ssrc);

  // --- layer 1: MFMA GEMM (direct f32 A) + fused logits, then aggregation ---
  k_gemm1<<<dim3(GB1, 2), 256, 0, stream>>>(x, B1h, B1l, att_src1, att_dst1,
                                            h1b, as1, ad1, N);
  int wave_blocks = (N * 64 + 255) / 256;
  k_agg1<<<wave_blocks, 256, 0, stream>>>(h1b, as1, ad1, offsets, ssrc, b1, A2h, N);

  // --- layer 2 ---
  k_gemm2<<<GB2, 256, 0, stream>>>(A2h, B2h, B2l, att_src2, att_dst2,
                                   h2b, as2, ad2, N);
  k_agg2<<<wave_blocks, 256, 0, stream>>>(h2b, as2, ad2, offsets, ssrc, b2, hfin, N);

  // --- global mean pool ---
  k_pool<<<64, 256, 0, stream>>>(hfin, gstart, out);
}

// Round 15
// 255.798 us; speedup vs baseline: 1.2397x; 1.1420x over previous
//
#include <hip/hip_runtime.h>
#include <math.h>

// ---------------- problem constants (match reference) ----------------
// N=50000, F_IN=128, HID=64, HEADS1=4 (C1=256), NUM_GRAPHS=64, slope=0.2

typedef unsigned short ushort_t;
typedef __bf16 bf16x8 __attribute__((ext_vector_type(8)));
typedef float  f32x4  __attribute__((ext_vector_type(4)));

__device__ inline float bf2f(ushort_t u) { return __uint_as_float((unsigned)u << 16); }
__device__ inline ushort_t f2bf(float x) {            // round-to-nearest-even
  unsigned b = __float_as_uint(x);
  return (ushort_t)((b + 0x7fff + ((b >> 16) & 1)) >> 16);
}
__device__ inline float leaky(float v) { return (v > 0.f) ? v : 0.2f * v; }

__device__ inline f32x4 mfma16(bf16x8 a, bf16x8 b, f32x4 c) {
  return __builtin_amdgcn_mfma_f32_16x16x32_bf16(a, b, c, 0, 0, 0);
}

// ---------------- B-operand pack helper ----------------
// frag layout: frag-lane fl = frag*64+lane; lane l holds j=0..7 with
// col=(l&15), k = kt*32 + (l>>4)*8 + j. A uses same k-slot convention.
__device__ inline void packB_one(const float* __restrict__ B, ushort_t* __restrict__ bh,
                                 ushort_t* __restrict__ bl, int K, int Nn, int t) {
  int KT = K >> 5;
  int l = t & 63, fb = t >> 6;
  int nt = fb / KT, kt = fb - nt * KT;
  int col = nt * 16 + (l & 15);
  int k0 = kt * 32 + (l >> 4) * 8;
  ushort_t h[8], lo[8];
  #pragma unroll
  for (int j = 0; j < 8; ++j) {
    float v = B[(size_t)(k0 + j) * Nn + col];
    h[j] = f2bf(v);
    lo[j] = f2bf(v - bf2f(h[j]));
  }
  size_t o = (size_t)t * 8;
  *(ushort4*)(bh + o)     = make_ushort4(h[0], h[1], h[2], h[3]);
  *(ushort4*)(bh + o + 4) = make_ushort4(h[4], h[5], h[6], h[7]);
  *(ushort4*)(bl + o)     = make_ushort4(lo[0], lo[1], lo[2], lo[3]);
  *(ushort4*)(bl + o + 4) = make_ushort4(lo[4], lo[5], lo[6], lo[7]);
}

// ---------------- fused setup: hist+rank | gbounds | packB ----------------
// deg zeroed beforehand (hipMemsetAsync). Self-loops NOT counted; scan adds +1/node.
// hist stores each edge's rank within its dst group (atomicAdd return value).
__global__ void k_setup(const int* __restrict__ edst, int E, int* __restrict__ deg,
                        int* __restrict__ rank,
                        const int* __restrict__ batch, int N, int G,
                        int* __restrict__ gstart,
                        const float* __restrict__ W1, const float* __restrict__ W2,
                        ushort_t* __restrict__ B1h, ushort_t* __restrict__ B1l,
                        ushort_t* __restrict__ B2h, ushort_t* __restrict__ B2l,
                        int HB, int GBB) {
  int b = blockIdx.x, tid = threadIdx.x;
  if (b < HB) {
    int i = b * 256 + tid;
    if (i < E) rank[i] = atomicAdd(&deg[edst[i]], 1);
  } else if (b < HB + GBB) {
    int i = (b - HB) * 256 + tid;
    if (i < N) {
      int bb = batch[i];
      int bp = (i == 0) ? -1 : batch[i - 1];
      for (int g = bp + 1; g <= bb; ++g) gstart[g] = i;
      if (i == N - 1)
        for (int g = bb + 1; g <= G; ++g) gstart[g] = N;
    }
  } else {
    int t = (b - HB - GBB) * 256 + tid;
    if (t < 4096) packB_one(W1, B1h, B1l, 128, 256, t);            // 16 nf x 4 kt
    else if (t < 6144) packB_one(W2, B2h, B2l, 256, 64, t - 4096); // 4 nf x 8 kt
  }
}

// ---------------- 3-pass multi-block exclusive scan over (deg[i]+1) ----------------
__global__ void k_scan_bsum(const int* __restrict__ deg, int n, int* __restrict__ bsum) {
  __shared__ int ws[16];
  int tid = threadIdx.x, lane = tid & 63, wv = tid >> 6;
  int i = blockIdx.x * 1024 + tid;
  int v = (i < n) ? deg[i] + 1 : 0;
  #pragma unroll
  for (int off = 1; off < 64; off <<= 1) v += __shfl_xor(v, off);
  if (lane == 0) ws[wv] = v;
  __syncthreads();
  if (tid < 16) {
    int s = ws[tid];
    #pragma unroll
    for (int off = 1; off < 16; off <<= 1) s += __shfl_xor(s, off);
    if (tid == 0) bsum[blockIdx.x] = s;
  }
}

__global__ void k_scan_bbase(const int* __restrict__ bsum, int nb,
                             int* __restrict__ bbase, int* __restrict__ offsets, int n) {
  int lane = threadIdx.x & 63;
  int v = (lane < nb) ? bsum[lane] : 0;
  int x = v;
  #pragma unroll
  for (int off = 1; off < 64; off <<= 1) {
    int t = __shfl_up(x, off);
    if (lane >= off) x += t;
  }
  if (lane < nb) bbase[lane] = x - v;
  if (lane == nb - 1) offsets[n] = x;
}

__global__ void k_scan_final(const int* __restrict__ deg, int n,
                             const int* __restrict__ bbase,
                             int* __restrict__ offsets) {
  __shared__ int wsum[16];
  int tid = threadIdx.x, lane = tid & 63, wv = tid >> 6;
  int i = blockIdx.x * 1024 + tid;
  int v = (i < n) ? deg[i] + 1 : 0;
  int x = v;
  #pragma unroll
  for (int off = 1; off < 64; off <<= 1) {
    int t = __shfl_up(x, off);
    if (lane >= off) x += t;
  }
  if (lane == 63) wsum[wv] = x;
  __syncthreads();
  if (wv == 0 && lane < 16) {
    int s = wsum[lane];
    #pragma unroll
    for (int off = 1; off < 16; off <<= 1) {
      int t = __shfl_up(s, off);
      if (lane >= off) s += t;
    }
    wsum[lane] = s;
  }
  __syncthreads();
  int wbase = (wv == 0) ? 0 : wsum[wv - 1];
  int incl = bbase[blockIdx.x] + wbase + x;
  if (i < n) offsets[i] = incl - v;
}

// ---------------- scatter: ATOMIC-FREE (pos = offsets[d] + rank[i]) ----------------
__global__ void k_scatter(const int* __restrict__ esrc, const int* __restrict__ edst,
                          const int* __restrict__ rank, const int* __restrict__ offsets,
                          int E, int N, int* __restrict__ ssrc) {
  int i = blockIdx.x * blockDim.x + threadIdx.x;
  int EE = E + N;
  if (i >= EE) return;
  if (i < E) {
    int d = edst[i];
    ssrc[offsets[d] + rank[i]] = esrc[i];
  } else {
    int d = i - E;                       // self-loop: last slot of node d's segment
    ssrc[offsets[d + 1] - 1] = d;
  }
}

// ---------------- MFMA GEMM + fused attention logits (device body) ----------------
// TERMS==3: A loaded DIRECTLY from f32 (in-register hi/lo split), 3-term product.
// TERMS==2: A from packed bf16 frags (Ah), 2-term product.
template<int KT, int TERMS, int WM>
__device__ void gemm_att_body(int bx, int by,
                              const float* __restrict__ Af32, const ushort_t* __restrict__ Ah,
                              const ushort_t* __restrict__ Bh, const ushort_t* __restrict__ Bl,
                              const float* __restrict__ a_srcW, const float* __restrict__ a_dstW,
                              ushort_t* __restrict__ hb, float* __restrict__ as_,
                              float* __restrict__ ad_, int M, int Nn, int H) {
  const int tid = threadIdx.x;
  const int w = tid >> 6, lane = tid & 63;
  const int wm = w & (WM - 1), wn = w / WM;
  const int m0w = bx * (WM * 32) + wm * 32;
  const int n0  = by * ((4 / WM) * 64) + wn * 64;
  const int head = n0 >> 6;
  const int mt0 = m0w >> 4, nt0 = n0 >> 4;

  const float* pX[2];
  int rowmi[2];
  const ushort_t* pAh[2];
  #pragma unroll
  for (int mi = 0; mi < 2; ++mi) {
    if constexpr (TERMS == 3) {
      rowmi[mi] = (mt0 + mi) * 16 + (lane & 15);
      pX[mi] = Af32 + (size_t)rowmi[mi] * (KT * 32) + ((lane >> 4) << 3);
    } else {
      size_t fa = (size_t)(mt0 + mi) * KT;
      pAh[mi] = Ah + fa * 512 + (size_t)lane * 8;
    }
  }
  const ushort_t* pBh[4];
  const ushort_t* pBl[4];
  #pragma unroll
  for (int ni = 0; ni < 4; ++ni) {
    size_t fb = (size_t)(nt0 + ni) * KT;
    pBh[ni] = Bh + fb * 512 + (size_t)lane * 8;
    pBl[ni] = Bl + fb * 512 + (size_t)lane * 8;
  }

  f32x4 acc[2][4];
  #pragma unroll
  for (int mi = 0; mi < 2; ++mi)
    #pragma unroll
    for (int ni = 0; ni < 4; ++ni)
      acc[mi][ni] = (f32x4){0.f, 0.f, 0.f, 0.f};

  for (int kt = 0; kt < KT; ++kt) {
    const size_t ko = (size_t)kt * 512;
    bf16x8 ahf[2], alf[2], bhf[4], blf[4];
    #pragma unroll
    for (int mi = 0; mi < 2; ++mi) {
      if constexpr (TERMS == 3) {
        float v[8] = {0.f, 0.f, 0.f, 0.f, 0.f, 0.f, 0.f, 0.f};
        if (rowmi[mi] < M) {
          float4 a = *(const float4*)(pX[mi] + kt * 32);
          float4 b = *(const float4*)(pX[mi] + kt * 32 + 4);
          v[0] = a.x; v[1] = a.y; v[2] = a.z; v[3] = a.w;
          v[4] = b.x; v[5] = b.y; v[6] = b.z; v[7] = b.w;
        }
        union { ushort_t u[8]; bf16x8 f; } uh, ul;
        #pragma unroll
        for (int j = 0; j < 8; ++j) {
          uh.u[j] = f2bf(v[j]);
          ul.u[j] = f2bf(v[j] - bf2f(uh.u[j]));
        }
        ahf[mi] = uh.f;
        alf[mi] = ul.f;
      } else {
        ahf[mi] = *(const bf16x8*)(pAh[mi] + ko);
      }
    }
    #pragma unroll
    for (int ni = 0; ni < 4; ++ni) {
      bhf[ni] = *(const bf16x8*)(pBh[ni] + ko);
      blf[ni] = *(const bf16x8*)(pBl[ni] + ko);
    }
    #pragma unroll
    for (int mi = 0; mi < 2; ++mi)
      #pragma unroll
      for (int ni = 0; ni < 4; ++ni) {
        if constexpr (TERMS == 3)
          acc[mi][ni] = mfma16(alf[mi], bhf[ni], acc[mi][ni]);
        acc[mi][ni] = mfma16(ahf[mi], blf[ni], acc[mi][ni]);
        acc[mi][ni] = mfma16(ahf[mi], bhf[ni], acc[mi][ni]);
      }
  }

  // epilogue: per-row head dots + bf16 store
  // D mapping: col = (lane&15) + ni*16, row = (lane>>4)*4 + reg + mi*16
  const int c16 = lane & 15, q = lane >> 4;
  float sv[4], dv[4];
  #pragma unroll
  for (int ni = 0; ni < 4; ++ni) {
    sv[ni] = a_srcW[head * 64 + ni * 16 + c16];
    dv[ni] = a_dstW[head * 64 + ni * 16 + c16];
  }
  #pragma unroll
  for (int mi = 0; mi < 2; ++mi) {
    #pragma unroll
    for (int r = 0; r < 4; ++r) {
      int gr = m0w + mi * 16 + q * 4 + r;
      float ps = acc[mi][0][r] * sv[0] + acc[mi][1][r] * sv[1] +
                 acc[mi][2][r] * sv[2] + acc[mi][3][r] * sv[3];
      float pd = acc[mi][0][r] * dv[0] + acc[mi][1][r] * dv[1] +
                 acc[mi][2][r] * dv[2] + acc[mi][3][r] * dv[3];
      #pragma unroll
      for (int off = 1; off < 16; off <<= 1) {
        ps += __shfl_xor(ps, off);
        pd += __shfl_xor(pd, off);
      }
      if (gr < M) {
        #pragma unroll
        for (int ni = 0; ni < 4; ++ni)
          hb[(size_t)gr * Nn + n0 + ni * 16 + c16] = f2bf(acc[mi][ni][r]);
        if (c16 == 0) { as_[gr * H + head] = ps; ad_[gr * H + head] = pd; }
      }
    }
  }
}

__global__ __launch_bounds__(256)
void k_gemm1(const float* __restrict__ x,
             const ushort_t* __restrict__ B1h, const ushort_t* __restrict__ B1l,
             const float* __restrict__ as_w, const float* __restrict__ ad_w,
             ushort_t* __restrict__ h1b, float* __restrict__ as1,
             float* __restrict__ ad1, int M) {
  gemm_att_body<4, 3, 2>(blockIdx.x, blockIdx.y, x, nullptr, B1h, B1l,
                         as_w, ad_w, h1b, as1, ad1, M, 256, 4);
}

__global__ __launch_bounds__(256)
void k_gemm2(const ushort_t* __restrict__ A2h,
             const ushort_t* __restrict__ B2h, const ushort_t* __restrict__ B2l,
             const float* __restrict__ as_w, const float* __restrict__ ad_w,
             ushort_t* __restrict__ h2b, float* __restrict__ as2,
             float* __restrict__ ad2, int M) {
  gemm_att_body<8, 2, 4>(blockIdx.x, 0, nullptr, A2h, B2h, B2l,
                         as_w, ad_w, h2b, as2, ad2, M, 64, 1);
}

// ---------------- layer-1 aggregation (inline no-max weights, unroll-8) ----------------
// w = exp(leaky(as1[s]+ad1[wid])) computed in-kernel: as1 load is a broadcast
// across the 16 lanes of a head group. Output written in gemm2 A-frag layout.
__global__ void k_agg1(const ushort_t* __restrict__ h1b, const float* __restrict__ as1,
                       const float* __restrict__ ad1, const int* __restrict__ offs,
                       const int* __restrict__ ssrc, const float* __restrict__ b1,
                       ushort_t* __restrict__ a2h, int N) {
  int gt = blockIdx.x * blockDim.x + threadIdx.x;
  int wid = gt >> 6, lane = gt & 63;
  if (wid >= N) return;
  int head = lane >> 4, sub = lane & 15, coff = sub << 2;
  int start = offs[wid], end = offs[wid + 1];
  float ad = ad1[wid * 4 + head];

  float denom = 0.f;
  float4 acc = make_float4(0.f, 0.f, 0.f, 0.f);
  int e = start;
  for (; e + 8 <= end; e += 8) {
    int s[8]; float w[8]; ushort4 g[8];
    #pragma unroll
    for (int j = 0; j < 8; ++j) s[j] = ssrc[e + j];
    #pragma unroll
    for (int j = 0; j < 8; ++j)
      g[j] = *(const ushort4*)(h1b + (size_t)s[j] * 256 + head * 64 + coff);
    #pragma unroll
    for (int j = 0; j < 8; ++j)
      w[j] = __expf(leaky(as1[s[j] * 4 + head] + ad));
    #pragma unroll
    for (int j = 0; j < 8; ++j) {
      denom += w[j];
      acc.x += w[j] * bf2f(g[j].x);
      acc.y += w[j] * bf2f(g[j].y);
      acc.z += w[j] * bf2f(g[j].z);
      acc.w += w[j] * bf2f(g[j].w);
    }
  }
  for (; e + 4 <= end; e += 4) {
    int s[4]; float w[4]; ushort4 g[4];
    #pragma unroll
    for (int j = 0; j < 4; ++j) s[j] = ssrc[e + j];
    #pragma unroll
    for (int j = 0; j < 4; ++j)
      g[j] = *(const ushort4*)(h1b + (size_t)s[j] * 256 + head * 64 + coff);
    #pragma unroll
    for (int j = 0; j < 4; ++j)
      w[j] = __expf(leaky(as1[s[j] * 4 + head] + ad));
    #pragma unroll
    for (int j = 0; j < 4; ++j) {
      denom += w[j];
      acc.x += w[j] * bf2f(g[j].x);
      acc.y += w[j] * bf2f(g[j].y);
      acc.z += w[j] * bf2f(g[j].z);
      acc.w += w[j] * bf2f(g[j].w);
    }
  }
  for (; e < end; ++e) {
    int s = ssrc[e];
    float w = __expf(leaky(as1[s * 4 + head] + ad));
    ushort4 g = *(const ushort4*)(h1b + (size_t)s * 256 + head * 64 + coff);
    denom += w;
    acc.x += w * bf2f(g.x); acc.y += w * bf2f(g.y);
    acc.z += w * bf2f(g.z); acc.w += w * bf2f(g.w);
  }
  float inv = 1.f / denom;
  float4 bv = *(const float4*)(b1 + head * 64 + coff);
  // packed write into gemm2 A-fragment layout
  int c0 = head * 64 + coff;
  int fa = (wid >> 4) * 8 + (c0 >> 5);
  int fl = (wid & 15) | (((c0 >> 3) & 3) << 4);
  size_t addr = ((size_t)fa * 64 + fl) * 8 + (c0 & 7);
  ushort4 o;
  o.x = f2bf(fmaxf(acc.x * inv + bv.x, 0.f));
  o.y = f2bf(fmaxf(acc.y * inv + bv.y, 0.f));
  o.z = f2bf(fmaxf(acc.z * inv + bv.z, 0.f));
  o.w = f2bf(fmaxf(acc.w * inv + bv.w, 0.f));
  *(ushort4*)(a2h + addr) = o;
}

// ---------------- layer-2 aggregation: half-wave pairing, inline weights ----------------
__global__ void k_agg2(const ushort_t* __restrict__ h2b, const float* __restrict__ as2,
                       const float* __restrict__ ad2, const int* __restrict__ offs,
                       const int* __restrict__ ssrc, const float* __restrict__ b2,
                       float* __restrict__ hfin, int N) {
  int gt = blockIdx.x * blockDim.x + threadIdx.x;
  int wid = gt >> 6, lane = gt & 63;
  if (wid >= N) return;
  int half = lane >> 5, li = lane & 31;
  int start = offs[wid], end = offs[wid + 1];
  float ad = ad2[wid];

  float dn = 0.f, acc0 = 0.f, acc1 = 0.f;
  int e = start;
  for (; e + 8 <= end; e += 8) {
    int e0 = e + half, e1 = e + 2 + half, e2 = e + 4 + half, e3 = e + 6 + half;
    int s0 = ssrc[e0], s1 = ssrc[e1], s2 = ssrc[e2], s3 = ssrc[e3];
    unsigned g0 = *(const unsigned*)(h2b + (size_t)s0 * 64 + li * 2);
    unsigned g1 = *(const unsigned*)(h2b + (size_t)s1 * 64 + li * 2);
    unsigned g2 = *(const unsigned*)(h2b + (size_t)s2 * 64 + li * 2);
    unsigned g3 = *(const unsigned*)(h2b + (size_t)s3 * 64 + li * 2);
    float wa = __expf(leaky(as2[s0] + ad));
    float wb = __expf(leaky(as2[s1] + ad));
    float wc = __expf(leaky(as2[s2] + ad));
    float wd = __expf(leaky(as2[s3] + ad));
    dn += (wa + wb) + (wc + wd);
    acc0 += wa * __uint_as_float(g0 << 16) + wb * __uint_as_float(g1 << 16)
          + wc * __uint_as_float(g2 << 16) + wd * __uint_as_float(g3 << 16);
    acc1 += wa * __uint_as_float(g0 & 0xffff0000u) + wb * __uint_as_float(g1 & 0xffff0000u)
          + wc * __uint_as_float(g2 & 0xffff0000u) + wd * __uint_as_float(g3 & 0xffff0000u);
  }
  for (; e + 2 <= end; e += 2) {
    int e0 = e + half;
    int s0 = ssrc[e0];
    float wa = __expf(leaky(as2[s0] + ad));
    unsigned g0 = *(const unsigned*)(h2b + (size_t)s0 * 64 + li * 2);
    dn += wa;
    acc0 += wa * __uint_as_float(g0 << 16);
    acc1 += wa * __uint_as_float(g0 & 0xffff0000u);
  }
  if (e < end && half == 0) {   // odd leftover edge
    int s0 = ssrc[e];
    float wa = __expf(leaky(as2[s0] + ad));
    unsigned g0 = *(const unsigned*)(h2b + (size_t)s0 * 64 + li * 2);
    dn += wa;
    acc0 += wa * __uint_as_float(g0 << 16);
    acc1 += wa * __uint_as_float(g0 & 0xffff0000u);
  }
  acc0 += __shfl_xor(acc0, 32);
  acc1 += __shfl_xor(acc1, 32);
  dn   += __shfl_xor(dn, 32);
  if (half == 0) {
    float inv = 1.f / dn;
    float2 bv = *(const float2*)(b2 + li * 2);
    float2 o;
    o.x = acc0 * inv + bv.x;
    o.y = acc1 * inv + bv.y;
    *(float2*)(hfin + (size_t)wid * 64 + li * 2) = o;
  }
}

// ---------------- global mean pool (batch is sorted) ----------------
__global__ void k_pool(const float* __restrict__ hfin, const int* __restrict__ gstart,
                       float* __restrict__ out) {
  int g = blockIdx.x;
  int c = threadIdx.x & 63, r = threadIdx.x >> 6;
  int start = gstart[g], cnt = gstart[g + 1] - start;
  float acc = 0.f;
  for (int i = r; i < cnt; i += 4)
    acc += hfin[(size_t)(start + i) * 64 + c];
  __shared__ float red[256];
  red[threadIdx.x] = acc;
  __syncthreads();
  if (r == 0)
    out[g * 64 + c] = (red[c] + red[64 + c] + red[128 + c] + red[192 + c]) /
                      fmaxf((float)cnt, 1.f);
}

// ---------------- launcher ----------------
extern "C" void kernel_launch(void* const* d_in, const int* in_sizes, int n_in,
                              void* d_out, int out_size, void* d_ws, size_t ws_size,
                              hipStream_t stream) {
  const float* x        = (const float*)d_in[0];
  const int*   ei       = (const int*)d_in[1];
  const int*   batch    = (const int*)d_in[2];
  const float* W1       = (const float*)d_in[3];
  const float* att_src1 = (const float*)d_in[4];
  const float* att_dst1 = (const float*)d_in[5];
  const float* b1       = (const float*)d_in[6];
  const float* W2       = (const float*)d_in[7];
  const float* att_src2 = (const float*)d_in[8];
  const float* att_dst2 = (const float*)d_in[9];
  const float* b2       = (const float*)d_in[10];
  float* out = (float*)d_out;

  const int N = in_sizes[0] / 128;   // 50000
  const int E = in_sizes[1] / 2;     // 800000
  const int EE = E + N;
  const int* esrc = ei;
  const int* edst = ei + E;

  const int GB2 = (N + 127) / 128;       // gemm2 blocks (128 rows)
  const int GB1 = GB2 * 2;               // gemm1 x-blocks (64 rows)
  const int MF  = GB2 * 8;               // padded m-frags (rows/16)
  const int NB  = (N + 1023) / 1024;     // scan blocks (<= 64)
  const int HB  = (E + 255) / 256;       // hist blocks
  const int GBB = (N + 255) / 256;       // gbounds blocks
  const int SCB = (EE + 255) / 256;      // scatter blocks (1 edge/thread)

  // workspace carve (256B aligned)
  char* p = (char*)d_ws;
  auto alloc = [&](size_t bytes) -> void* {
    void* r = (void*)p;
    p += (bytes + 255) & ~(size_t)255;
    return r;
  };
  ushort_t* A2h  = (ushort_t*)alloc((size_t)MF * 8 * 64 * 16);  // written by k_agg1
  ushort_t* B1h  = (ushort_t*)alloc((size_t)16 * 4 * 64 * 16);
  ushort_t* B1l  = (ushort_t*)alloc((size_t)16 * 4 * 64 * 16);
  ushort_t* B2h  = (ushort_t*)alloc((size_t)4 * 8 * 64 * 16);
  ushort_t* B2l  = (ushort_t*)alloc((size_t)4 * 8 * 64 * 16);
  ushort_t* h1b  = (ushort_t*)alloc((size_t)N * 256 * 2);
  ushort_t* h2b  = (ushort_t*)alloc((size_t)N * 64 * 2);
  float*    hfin = (float*)alloc((size_t)N * 64 * 4);
  float*    as1  = (float*)alloc((size_t)N * 4 * 4);
  float*    ad1  = (float*)alloc((size_t)N * 4 * 4);
  float*    as2  = (float*)alloc((size_t)N * 4);
  float*    ad2  = (float*)alloc((size_t)N * 4);
  int*  deg     = (int*)alloc((size_t)N * 4);
  int*  rank    = (int*)alloc((size_t)E * 4);
  int*  offsets = (int*)alloc((size_t)(N + 1) * 4);
  int*  ssrc    = (int*)alloc((size_t)EE * 4);
  int*  bsum    = (int*)alloc(64 * 4);
  int*  bbase   = (int*)alloc(64 * 4);
  int*  gstart  = (int*)alloc(65 * 4);

  // --- zero degree array (async, capture-safe) ---
  hipMemsetAsync(deg, 0, (size_t)N * 4, stream);

  // --- fused setup: hist+rank | gbounds | packB ---
  k_setup<<<HB + GBB + 24, 256, 0, stream>>>(edst, E, deg, rank, batch, N, 64, gstart,
                                             W1, W2, B1h, B1l, B2h, B2l, HB, GBB);

  // --- scan over deg+1 ---
  k_scan_bsum<<<NB, 1024, 0, stream>>>(deg, N, bsum);
  k_scan_bbase<<<1, 64, 0, stream>>>(bsum, NB, bbase, offsets, N);
  k_scan_final<<<NB, 1024, 0, stream>>>(deg, N, bbase, offsets);

  // --- scatter: atomic-free, 1 edge/thread ---
  k_scatter<<<SCB, 256, 0, stream>>>(esrc, edst, rank, offsets, E, N, ssrc);

  // --- layer 1: MFMA GEMM (direct f32 A) + fused logits, then aggregation ---
  k_gemm1<<<dim3(GB1, 2), 256, 0, stream>>>(x, B1h, B1l, att_src1, att_dst1,
                                            h1b, as1, ad1, N);
  int wave_blocks = (N * 64 + 255) / 256;
  k_agg1<<<wave_blocks, 256, 0, stream>>>(h1b, as1, ad1, offsets, ssrc, b1, A2h, N);

  // --- layer 2 ---
  k_gemm2<<<GB2, 256, 0, stream>>>(A2h, B2h, B2l, att_src2, att_dst2,
                                   h2b, as2, ad2, N);
  k_agg2<<<wave_blocks, 256, 0, stream>>>(h2b, as2, ad2, offsets, ssrc, b2, hfin, N);

  // --- global mean pool ---
  k_pool<<<64, 256, 0, stream>>>(hfin, gstart, out);
}

// Round 16
// 254.717 us; speedup vs baseline: 1.2450x; 1.0042x over previous
//
#include <hip/hip_runtime.h>
#include <math.h>

// ---------------- problem constants (match reference) ----------------
// N=50000, F_IN=128, HID=64, HEADS1=4 (C1=256), NUM_GRAPHS=64, slope=0.2

typedef unsigned short ushort_t;
typedef __bf16 bf16x8 __attribute__((ext_vector_type(8)));
typedef float  f32x4  __attribute__((ext_vector_type(4)));

__device__ inline float bf2f(ushort_t u) { return __uint_as_float((unsigned)u << 16); }
__device__ inline ushort_t f2bf(float x) {            // round-to-nearest-even
  unsigned b = __float_as_uint(x);
  return (ushort_t)((b + 0x7fff + ((b >> 16) & 1)) >> 16);
}
__device__ inline float leaky(float v) { return (v > 0.f) ? v : 0.2f * v; }

__device__ inline f32x4 mfma16(bf16x8 a, bf16x8 b, f32x4 c) {
  return __builtin_amdgcn_mfma_f32_16x16x32_bf16(a, b, c, 0, 0, 0);
}

// ---------------- B-operand pack helper ----------------
// frag layout: frag-lane fl = frag*64+lane; lane l holds j=0..7 with
// col=(l&15), k = kt*32 + (l>>4)*8 + j. A uses same k-slot convention.
__device__ inline void packB_one(const float* __restrict__ B, ushort_t* __restrict__ bh,
                                 ushort_t* __restrict__ bl, int K, int Nn, int t) {
  int KT = K >> 5;
  int l = t & 63, fb = t >> 6;
  int nt = fb / KT, kt = fb - nt * KT;
  int col = nt * 16 + (l & 15);
  int k0 = kt * 32 + (l >> 4) * 8;
  ushort_t h[8], lo[8];
  #pragma unroll
  for (int j = 0; j < 8; ++j) {
    float v = B[(size_t)(k0 + j) * Nn + col];
    h[j] = f2bf(v);
    lo[j] = f2bf(v - bf2f(h[j]));
  }
  size_t o = (size_t)t * 8;
  *(ushort4*)(bh + o)     = make_ushort4(h[0], h[1], h[2], h[3]);
  *(ushort4*)(bh + o + 4) = make_ushort4(h[4], h[5], h[6], h[7]);
  *(ushort4*)(bl + o)     = make_ushort4(lo[0], lo[1], lo[2], lo[3]);
  *(ushort4*)(bl + o + 4) = make_ushort4(lo[4], lo[5], lo[6], lo[7]);
}

// ---------------- fused setup: hist+rank | gbounds | packB ----------------
// deg zeroed beforehand (hipMemsetAsync). Self-loops NOT counted; scan adds +1/node.
// hist stores each edge's rank within its dst group (atomicAdd return value).
__global__ void k_setup(const int* __restrict__ edst, int E, int* __restrict__ deg,
                        int* __restrict__ rank,
                        const int* __restrict__ batch, int N, int G,
                        int* __restrict__ gstart,
                        const float* __restrict__ W1, const float* __restrict__ W2,
                        ushort_t* __restrict__ B1h, ushort_t* __restrict__ B1l,
                        ushort_t* __restrict__ B2h, ushort_t* __restrict__ B2l,
                        int HB, int GBB) {
  int b = blockIdx.x, tid = threadIdx.x;
  if (b < HB) {
    int i = b * 256 + tid;
    if (i < E) rank[i] = atomicAdd(&deg[edst[i]], 1);
  } else if (b < HB + GBB) {
    int i = (b - HB) * 256 + tid;
    if (i < N) {
      int bb = batch[i];
      int bp = (i == 0) ? -1 : batch[i - 1];
      for (int g = bp + 1; g <= bb; ++g) gstart[g] = i;
      if (i == N - 1)
        for (int g = bb + 1; g <= G; ++g) gstart[g] = N;
    }
  } else {
    int t = (b - HB - GBB) * 256 + tid;
    if (t < 4096) packB_one(W1, B1h, B1l, 128, 256, t);            // 16 nf x 4 kt
    else if (t < 6144) packB_one(W2, B2h, B2l, 256, 64, t - 4096); // 4 nf x 8 kt
  }
}

// ---------------- 3-pass multi-block exclusive scan over (deg[i]+1) ----------------
__global__ void k_scan_bsum(const int* __restrict__ deg, int n, int* __restrict__ bsum) {
  __shared__ int ws[16];
  int tid = threadIdx.x, lane = tid & 63, wv = tid >> 6;
  int i = blockIdx.x * 1024 + tid;
  int v = (i < n) ? deg[i] + 1 : 0;
  #pragma unroll
  for (int off = 1; off < 64; off <<= 1) v += __shfl_xor(v, off);
  if (lane == 0) ws[wv] = v;
  __syncthreads();
  if (tid < 16) {
    int s = ws[tid];
    #pragma unroll
    for (int off = 1; off < 16; off <<= 1) s += __shfl_xor(s, off);
    if (tid == 0) bsum[blockIdx.x] = s;
  }
}

__global__ void k_scan_bbase(const int* __restrict__ bsum, int nb,
                             int* __restrict__ bbase, int* __restrict__ offsets, int n) {
  int lane = threadIdx.x & 63;
  int v = (lane < nb) ? bsum[lane] : 0;
  int x = v;
  #pragma unroll
  for (int off = 1; off < 64; off <<= 1) {
    int t = __shfl_up(x, off);
    if (lane >= off) x += t;
  }
  if (lane < nb) bbase[lane] = x - v;
  if (lane == nb - 1) offsets[n] = x;
}

__global__ void k_scan_final(const int* __restrict__ deg, int n,
                             const int* __restrict__ bbase,
                             int* __restrict__ offsets) {
  __shared__ int wsum[16];
  int tid = threadIdx.x, lane = tid & 63, wv = tid >> 6;
  int i = blockIdx.x * 1024 + tid;
  int v = (i < n) ? deg[i] + 1 : 0;
  int x = v;
  #pragma unroll
  for (int off = 1; off < 64; off <<= 1) {
    int t = __shfl_up(x, off);
    if (lane >= off) x += t;
  }
  if (lane == 63) wsum[wv] = x;
  __syncthreads();
  if (wv == 0 && lane < 16) {
    int s = wsum[lane];
    #pragma unroll
    for (int off = 1; off < 16; off <<= 1) {
      int t = __shfl_up(s, off);
      if (lane >= off) s += t;
    }
    wsum[lane] = s;
  }
  __syncthreads();
  int wbase = (wv == 0) ? 0 : wsum[wv - 1];
  int incl = bbase[blockIdx.x] + wbase + x;
  if (i < n) offsets[i] = incl - v;
}

// ---------------- scatter: ATOMIC-FREE (pos = offsets[d] + rank[i]) ----------------
__global__ void k_scatter(const int* __restrict__ esrc, const int* __restrict__ edst,
                          const int* __restrict__ rank, const int* __restrict__ offsets,
                          int E, int N, int* __restrict__ ssrc) {
  int i = blockIdx.x * blockDim.x + threadIdx.x;
  int EE = E + N;
  if (i >= EE) return;
  if (i < E) {
    int d = edst[i];
    ssrc[offsets[d] + rank[i]] = esrc[i];
  } else {
    int d = i - E;                       // self-loop: last slot of node d's segment
    ssrc[offsets[d + 1] - 1] = d;
  }
}

// ---------------- MFMA GEMM + fused attention logits (device body) ----------------
// TERMS==3: A loaded DIRECTLY from f32 (in-register hi/lo split), 3-term product.
// TERMS==2: A from packed bf16 frags (Ah), 2-term product.
// WM=1: block = 32 rows x 4*64 cols (all heads); 4 waves share A rows (L1 reuse).
template<int KT, int TERMS, int WM>
__device__ void gemm_att_body(int bx, int by,
                              const float* __restrict__ Af32, const ushort_t* __restrict__ Ah,
                              const ushort_t* __restrict__ Bh, const ushort_t* __restrict__ Bl,
                              const float* __restrict__ a_srcW, const float* __restrict__ a_dstW,
                              ushort_t* __restrict__ hb, float* __restrict__ as_,
                              float* __restrict__ ad_, int M, int Nn, int H) {
  const int tid = threadIdx.x;
  const int w = tid >> 6, lane = tid & 63;
  const int wm = w & (WM - 1), wn = w / WM;
  const int m0w = bx * (WM * 32) + wm * 32;
  const int n0  = by * ((4 / WM) * 64) + wn * 64;
  const int head = n0 >> 6;
  const int mt0 = m0w >> 4, nt0 = n0 >> 4;

  const float* pX[2];
  int rowmi[2];
  const ushort_t* pAh[2];
  #pragma unroll
  for (int mi = 0; mi < 2; ++mi) {
    if constexpr (TERMS == 3) {
      rowmi[mi] = (mt0 + mi) * 16 + (lane & 15);
      pX[mi] = Af32 + (size_t)rowmi[mi] * (KT * 32) + ((lane >> 4) << 3);
    } else {
      size_t fa = (size_t)(mt0 + mi) * KT;
      pAh[mi] = Ah + fa * 512 + (size_t)lane * 8;
    }
  }
  const ushort_t* pBh[4];
  const ushort_t* pBl[4];
  #pragma unroll
  for (int ni = 0; ni < 4; ++ni) {
    size_t fb = (size_t)(nt0 + ni) * KT;
    pBh[ni] = Bh + fb * 512 + (size_t)lane * 8;
    pBl[ni] = Bl + fb * 512 + (size_t)lane * 8;
  }

  f32x4 acc[2][4];
  #pragma unroll
  for (int mi = 0; mi < 2; ++mi)
    #pragma unroll
    for (int ni = 0; ni < 4; ++ni)
      acc[mi][ni] = (f32x4){0.f, 0.f, 0.f, 0.f};

  for (int kt = 0; kt < KT; ++kt) {
    const size_t ko = (size_t)kt * 512;
    bf16x8 ahf[2], alf[2], bhf[4], blf[4];
    #pragma unroll
    for (int mi = 0; mi < 2; ++mi) {
      if constexpr (TERMS == 3) {
        float v[8] = {0.f, 0.f, 0.f, 0.f, 0.f, 0.f, 0.f, 0.f};
        if (rowmi[mi] < M) {
          float4 a = *(const float4*)(pX[mi] + kt * 32);
          float4 b = *(const float4*)(pX[mi] + kt * 32 + 4);
          v[0] = a.x; v[1] = a.y; v[2] = a.z; v[3] = a.w;
          v[4] = b.x; v[5] = b.y; v[6] = b.z; v[7] = b.w;
        }
        union { ushort_t u[8]; bf16x8 f; } uh, ul;
        #pragma unroll
        for (int j = 0; j < 8; ++j) {
          uh.u[j] = f2bf(v[j]);
          ul.u[j] = f2bf(v[j] - bf2f(uh.u[j]));
        }
        ahf[mi] = uh.f;
        alf[mi] = ul.f;
      } else {
        ahf[mi] = *(const bf16x8*)(pAh[mi] + ko);
      }
    }
    #pragma unroll
    for (int ni = 0; ni < 4; ++ni) {
      bhf[ni] = *(const bf16x8*)(pBh[ni] + ko);
      blf[ni] = *(const bf16x8*)(pBl[ni] + ko);
    }
    #pragma unroll
    for (int mi = 0; mi < 2; ++mi)
      #pragma unroll
      for (int ni = 0; ni < 4; ++ni) {
        if constexpr (TERMS == 3)
          acc[mi][ni] = mfma16(alf[mi], bhf[ni], acc[mi][ni]);
        acc[mi][ni] = mfma16(ahf[mi], blf[ni], acc[mi][ni]);
        acc[mi][ni] = mfma16(ahf[mi], bhf[ni], acc[mi][ni]);
      }
  }

  // epilogue: per-row head dots + bf16 store
  // D mapping: col = (lane&15) + ni*16, row = (lane>>4)*4 + reg + mi*16
  const int c16 = lane & 15, q = lane >> 4;
  float sv[4], dv[4];
  #pragma unroll
  for (int ni = 0; ni < 4; ++ni) {
    sv[ni] = a_srcW[head * 64 + ni * 16 + c16];
    dv[ni] = a_dstW[head * 64 + ni * 16 + c16];
  }
  #pragma unroll
  for (int mi = 0; mi < 2; ++mi) {
    #pragma unroll
    for (int r = 0; r < 4; ++r) {
      int gr = m0w + mi * 16 + q * 4 + r;
      float ps = acc[mi][0][r] * sv[0] + acc[mi][1][r] * sv[1] +
                 acc[mi][2][r] * sv[2] + acc[mi][3][r] * sv[3];
      float pd = acc[mi][0][r] * dv[0] + acc[mi][1][r] * dv[1] +
                 acc[mi][2][r] * dv[2] + acc[mi][3][r] * dv[3];
      #pragma unroll
      for (int off = 1; off < 16; off <<= 1) {
        ps += __shfl_xor(ps, off);
        pd += __shfl_xor(pd, off);
      }
      if (gr < M) {
        #pragma unroll
        for (int ni = 0; ni < 4; ++ni)
          hb[(size_t)gr * Nn + n0 + ni * 16 + c16] = f2bf(acc[mi][ni][r]);
        if (c16 == 0) { as_[gr * H + head] = ps; ad_[gr * H + head] = pd; }
      }
    }
  }
}

__global__ __launch_bounds__(256)
void k_gemm1(const float* __restrict__ x,
             const ushort_t* __restrict__ B1h, const ushort_t* __restrict__ B1l,
             const float* __restrict__ as_w, const float* __restrict__ ad_w,
             ushort_t* __restrict__ h1b, float* __restrict__ as1,
             float* __restrict__ ad1, int M) {
  // WM=1: 32 rows/block, all 4 heads in-block; x read once from HBM
  gemm_att_body<4, 3, 1>(blockIdx.x, 0, x, nullptr, B1h, B1l,
                         as_w, ad_w, h1b, as1, ad1, M, 256, 4);
}

__global__ __launch_bounds__(256)
void k_gemm2(const ushort_t* __restrict__ A2h,
             const ushort_t* __restrict__ B2h, const ushort_t* __restrict__ B2l,
             const float* __restrict__ as_w, const float* __restrict__ ad_w,
             ushort_t* __restrict__ h2b, float* __restrict__ as2,
             float* __restrict__ ad2, int M) {
  gemm_att_body<8, 2, 4>(blockIdx.x, 0, nullptr, A2h, B2h, B2l,
                         as_w, ad_w, h2b, as2, ad2, M, 64, 1);
}

// ---------------- layer-1 aggregation (inline no-max weights, unroll-8) ----------------
// w = exp(leaky(as1[s]+ad1[wid])) computed in-kernel: as1 load is a broadcast
// across the 16 lanes of a head group. Output written in gemm2 A-frag layout.
__global__ void k_agg1(const ushort_t* __restrict__ h1b, const float* __restrict__ as1,
                       const float* __restrict__ ad1, const int* __restrict__ offs,
                       const int* __restrict__ ssrc, const float* __restrict__ b1,
                       ushort_t* __restrict__ a2h, int N) {
  int gt = blockIdx.x * blockDim.x + threadIdx.x;
  int wid = gt >> 6, lane = gt & 63;
  if (wid >= N) return;
  int head = lane >> 4, sub = lane & 15, coff = sub << 2;
  int start = offs[wid], end = offs[wid + 1];
  float ad = ad1[wid * 4 + head];

  float denom = 0.f;
  float4 acc = make_float4(0.f, 0.f, 0.f, 0.f);
  int e = start;
  for (; e + 8 <= end; e += 8) {
    int s[8]; float w[8]; ushort4 g[8];
    #pragma unroll
    for (int j = 0; j < 8; ++j) s[j] = ssrc[e + j];
    #pragma unroll
    for (int j = 0; j < 8; ++j)
      g[j] = *(const ushort4*)(h1b + (size_t)s[j] * 256 + head * 64 + coff);
    #pragma unroll
    for (int j = 0; j < 8; ++j)
      w[j] = __expf(leaky(as1[s[j] * 4 + head] + ad));
    #pragma unroll
    for (int j = 0; j < 8; ++j) {
      denom += w[j];
      acc.x += w[j] * bf2f(g[j].x);
      acc.y += w[j] * bf2f(g[j].y);
      acc.z += w[j] * bf2f(g[j].z);
      acc.w += w[j] * bf2f(g[j].w);
    }
  }
  for (; e + 4 <= end; e += 4) {
    int s[4]; float w[4]; ushort4 g[4];
    #pragma unroll
    for (int j = 0; j < 4; ++j) s[j] = ssrc[e + j];
    #pragma unroll
    for (int j = 0; j < 4; ++j)
      g[j] = *(const ushort4*)(h1b + (size_t)s[j] * 256 + head * 64 + coff);
    #pragma unroll
    for (int j = 0; j < 4; ++j)
      w[j] = __expf(leaky(as1[s[j] * 4 + head] + ad));
    #pragma unroll
    for (int j = 0; j < 4; ++j) {
      denom += w[j];
      acc.x += w[j] * bf2f(g[j].x);
      acc.y += w[j] * bf2f(g[j].y);
      acc.z += w[j] * bf2f(g[j].z);
      acc.w += w[j] * bf2f(g[j].w);
    }
  }
  for (; e < end; ++e) {
    int s = ssrc[e];
    float w = __expf(leaky(as1[s * 4 + head] + ad));
    ushort4 g = *(const ushort4*)(h1b + (size_t)s * 256 + head * 64 + coff);
    denom += w;
    acc.x += w * bf2f(g.x); acc.y += w * bf2f(g.y);
    acc.z += w * bf2f(g.z); acc.w += w * bf2f(g.w);
  }
  float inv = 1.f / denom;
  float4 bv = *(const float4*)(b1 + head * 64 + coff);
  // packed write into gemm2 A-fragment layout
  int c0 = head * 64 + coff;
  int fa = (wid >> 4) * 8 + (c0 >> 5);
  int fl = (wid & 15) | (((c0 >> 3) & 3) << 4);
  size_t addr = ((size_t)fa * 64 + fl) * 8 + (c0 & 7);
  ushort4 o;
  o.x = f2bf(fmaxf(acc.x * inv + bv.x, 0.f));
  o.y = f2bf(fmaxf(acc.y * inv + bv.y, 0.f));
  o.z = f2bf(fmaxf(acc.z * inv + bv.z, 0.f));
  o.w = f2bf(fmaxf(acc.w * inv + bv.w, 0.f));
  *(ushort4*)(a2h + addr) = o;
}

// ---------------- layer-2 aggregation: half-wave pairing, inline weights ----------------
__global__ void k_agg2(const ushort_t* __restrict__ h2b, const float* __restrict__ as2,
                       const float* __restrict__ ad2, const int* __restrict__ offs,
                       const int* __restrict__ ssrc, const float* __restrict__ b2,
                       float* __restrict__ hfin, int N) {
  int gt = blockIdx.x * blockDim.x + threadIdx.x;
  int wid = gt >> 6, lane = gt & 63;
  if (wid >= N) return;
  int half = lane >> 5, li = lane & 31;
  int start = offs[wid], end = offs[wid + 1];
  float ad = ad2[wid];

  float dn = 0.f, acc0 = 0.f, acc1 = 0.f;
  int e = start;
  for (; e + 8 <= end; e += 8) {
    int e0 = e + half, e1 = e + 2 + half, e2 = e + 4 + half, e3 = e + 6 + half;
    int s0 = ssrc[e0], s1 = ssrc[e1], s2 = ssrc[e2], s3 = ssrc[e3];
    unsigned g0 = *(const unsigned*)(h2b + (size_t)s0 * 64 + li * 2);
    unsigned g1 = *(const unsigned*)(h2b + (size_t)s1 * 64 + li * 2);
    unsigned g2 = *(const unsigned*)(h2b + (size_t)s2 * 64 + li * 2);
    unsigned g3 = *(const unsigned*)(h2b + (size_t)s3 * 64 + li * 2);
    float wa = __expf(leaky(as2[s0] + ad));
    float wb = __expf(leaky(as2[s1] + ad));
    float wc = __expf(leaky(as2[s2] + ad));
    float wd = __expf(leaky(as2[s3] + ad));
    dn += (wa + wb) + (wc + wd);
    acc0 += wa * __uint_as_float(g0 << 16) + wb * __uint_as_float(g1 << 16)
          + wc * __uint_as_float(g2 << 16) + wd * __uint_as_float(g3 << 16);
    acc1 += wa * __uint_as_float(g0 & 0xffff0000u) + wb * __uint_as_float(g1 & 0xffff0000u)
          + wc * __uint_as_float(g2 & 0xffff0000u) + wd * __uint_as_float(g3 & 0xffff0000u);
  }
  for (; e + 2 <= end; e += 2) {
    int e0 = e + half;
    int s0 = ssrc[e0];
    float wa = __expf(leaky(as2[s0] + ad));
    unsigned g0 = *(const unsigned*)(h2b + (size_t)s0 * 64 + li * 2);
    dn += wa;
    acc0 += wa * __uint_as_float(g0 << 16);
    acc1 += wa * __uint_as_float(g0 & 0xffff0000u);
  }
  if (e < end && half == 0) {   // odd leftover edge
    int s0 = ssrc[e];
    float wa = __expf(leaky(as2[s0] + ad));
    unsigned g0 = *(const unsigned*)(h2b + (size_t)s0 * 64 + li * 2);
    dn += wa;
    acc0 += wa * __uint_as_float(g0 << 16);
    acc1 += wa * __uint_as_float(g0 & 0xffff0000u);
  }
  acc0 += __shfl_xor(acc0, 32);
  acc1 += __shfl_xor(acc1, 32);
  dn   += __shfl_xor(dn, 32);
  if (half == 0) {
    float inv = 1.f / dn;
    float2 bv = *(const float2*)(b2 + li * 2);
    float2 o;
    o.x = acc0 * inv + bv.x;
    o.y = acc1 * inv + bv.y;
    *(float2*)(hfin + (size_t)wid * 64 + li * 2) = o;
  }
}

// ---------------- global mean pool (batch is sorted) ----------------
__global__ void k_pool(const float* __restrict__ hfin, const int* __restrict__ gstart,
                       float* __restrict__ out) {
  int g = blockIdx.x;
  int c = threadIdx.x & 63, r = threadIdx.x >> 6;
  int start = gstart[g], cnt = gstart[g + 1] - start;
  float acc = 0.f;
  for (int i = r; i < cnt; i += 4)
    acc += hfin[(size_t)(start + i) * 64 + c];
  __shared__ float red[256];
  red[threadIdx.x] = acc;
  __syncthreads();
  if (r == 0)
    out[g * 64 + c] = (red[c] + red[64 + c] + red[128 + c] + red[192 + c]) /
                      fmaxf((float)cnt, 1.f);
}

// ---------------- launcher ----------------
extern "C" void kernel_launch(void* const* d_in, const int* in_sizes, int n_in,
                              void* d_out, int out_size, void* d_ws, size_t ws_size,
                              hipStream_t stream) {
  const float* x        = (const float*)d_in[0];
  const int*   ei       = (const int*)d_in[1];
  const int*   batch    = (const int*)d_in[2];
  const float* W1       = (const float*)d_in[3];
  const float* att_src1 = (const float*)d_in[4];
  const float* att_dst1 = (const float*)d_in[5];
  const float* b1       = (const float*)d_in[6];
  const float* W2       = (const float*)d_in[7];
  const float* att_src2 = (const float*)d_in[8];
  const float* att_dst2 = (const float*)d_in[9];
  const float* b2       = (const float*)d_in[10];
  float* out = (float*)d_out;

  const int N = in_sizes[0] / 128;   // 50000
  const int E = in_sizes[1] / 2;     // 800000
  const int EE = E + N;
  const int* esrc = ei;
  const int* edst = ei + E;

  const int GB2 = (N + 127) / 128;       // gemm2 blocks (128 rows)
  const int GB1 = (N + 31) / 32;         // gemm1 blocks (32 rows, all heads)
  const int MF  = GB2 * 8;               // padded m-frags (rows/16)
  const int NB  = (N + 1023) / 1024;     // scan blocks (<= 64)
  const int HB  = (E + 255) / 256;       // hist blocks
  const int GBB = (N + 255) / 256;       // gbounds blocks
  const int SCB = (EE + 255) / 256;      // scatter blocks (1 edge/thread)

  // workspace carve (256B aligned)
  char* p = (char*)d_ws;
  auto alloc = [&](size_t bytes) -> void* {
    void* r = (void*)p;
    p += (bytes + 255) & ~(size_t)255;
    return r;
  };
  ushort_t* A2h  = (ushort_t*)alloc((size_t)MF * 8 * 64 * 16);  // written by k_agg1
  ushort_t* B1h  = (ushort_t*)alloc((size_t)16 * 4 * 64 * 16);
  ushort_t* B1l  = (ushort_t*)alloc((size_t)16 * 4 * 64 * 16);
  ushort_t* B2h  = (ushort_t*)alloc((size_t)4 * 8 * 64 * 16);
  ushort_t* B2l  = (ushort_t*)alloc((size_t)4 * 8 * 64 * 16);
  ushort_t* h1b  = (ushort_t*)alloc((size_t)N * 256 * 2);
  ushort_t* h2b  = (ushort_t*)alloc((size_t)N * 64 * 2);
  float*    hfin = (float*)alloc((size_t)N * 64 * 4);
  float*    as1  = (float*)alloc((size_t)N * 4 * 4);
  float*    ad1  = (float*)alloc((size_t)N * 4 * 4);
  float*    as2  = (float*)alloc((size_t)N * 4);
  float*    ad2  = (float*)alloc((size_t)N * 4);
  int*  deg     = (int*)alloc((size_t)N * 4);
  int*  rank    = (int*)alloc((size_t)E * 4);
  int*  offsets = (int*)alloc((size_t)(N + 1) * 4);
  int*  ssrc    = (int*)alloc((size_t)EE * 4);
  int*  bsum    = (int*)alloc(64 * 4);
  int*  bbase   = (int*)alloc(64 * 4);
  int*  gstart  = (int*)alloc(65 * 4);

  // --- zero degree array (async, capture-safe) ---
  hipMemsetAsync(deg, 0, (size_t)N * 4, stream);

  // --- fused setup: hist+rank | gbounds | packB ---
  k_setup<<<HB + GBB + 24, 256, 0, stream>>>(edst, E, deg, rank, batch, N, 64, gstart,
                                             W1, W2, B1h, B1l, B2h, B2l, HB, GBB);

  // --- scan over deg+1 ---
  k_scan_bsum<<<NB, 1024, 0, stream>>>(deg, N, bsum);
  k_scan_bbase<<<1, 64, 0, stream>>>(bsum, NB, bbase, offsets, N);
  k_scan_final<<<NB, 1024, 0, stream>>>(deg, N, bbase, offsets);

  // --- scatter: atomic-free, 1 edge/thread ---
  k_scatter<<<SCB, 256, 0, stream>>>(esrc, edst, rank, offsets, E, N, ssrc);

  // --- layer 1: MFMA GEMM (direct f32 A, x read once) + fused logits ---
  k_gemm1<<<GB1, 256, 0, stream>>>(x, B1h, B1l, att_src1, att_dst1,
                                   h1b, as1, ad1, N);
  int wave_blocks = (N * 64 + 255) / 256;
  k_agg1<<<wave_blocks, 256, 0, stream>>>(h1b, as1, ad1, offsets, ssrc, b1, A2h, N);

  // --- layer 2 ---
  k_gemm2<<<GB2, 256, 0, stream>>>(A2h, B2h, B2l, att_src2, att_dst2,
                                   h2b, as2, ad2, N);
  k_agg2<<<wave_blocks, 256, 0, stream>>>(h2b, as2, ad2, offsets, ssrc, b2, hfin, N);

  // --- global mean pool ---
  k_pool<<<64, 256, 0, stream>>>(hfin, gstart, out);
}